// Round 4
// baseline (1719.313 us; speedup 1.0000x reference)
//
#include <hip/hip_runtime.h>
#include <hip/hip_cooperative_groups.h>
#include <math.h>

namespace cg = cooperative_groups;

#define DIMV 200
typedef unsigned short ushort;
typedef unsigned int uint;
typedef __attribute__((ext_vector_type(8))) __bf16  bf16x8;
typedef __attribute__((ext_vector_type(4))) float   f32x4;

static __device__ __forceinline__ int lower_bound(const int* __restrict__ a, int n, int key) {
    int lo = 0, hi = n;
    while (lo < hi) {
        int mid = (lo + hi) >> 1;
        if (a[mid] < key) lo = mid + 1; else hi = mid;
    }
    return lo;
}

static __device__ __forceinline__ float gate_fn(float u, float logit) {
    // bias = 1e-4: eps = (2b-1)*u + (1-b); sigmoid((log(eps)-log1p(-eps)+logit)/0.5)
    float ee = fmaf(u, -0.9998f, 0.9999f);
    float g  = (logf(ee) - log1pf(-ee) + logit) * 2.0f;
    return 1.0f / (1.0f + expf(-g));
}

static __device__ __forceinline__ ushort f2bf(float f) {
    unsigned int u = __float_as_uint(f);
    return (ushort)((u + 0x7fffu + ((u >> 16) & 1u)) >> 16);
}
// packed pair: low ushort = dim 2k, high ushort = dim 2k+1
static __device__ __forceinline__ float2 bfp2f(uint u) {
    float2 r;
    r.x = __uint_as_float(u << 16);
    r.y = __uint_as_float(u & 0xffff0000u);
    return r;
}
static __device__ __forceinline__ uint f2bfp(float a, float b) {
    return (uint)f2bf(a) | ((uint)f2bf(b) << 16);
}

static __device__ __forceinline__ void cvt8_store(ushort* dst, const float* src) {
    float4 a = *(const float4*)src;
    float4 b = *(const float4*)(src + 4);
    dst[0] = f2bf(a.x); dst[1] = f2bf(a.y); dst[2] = f2bf(a.z); dst[3] = f2bf(a.w);
    dst[4] = f2bf(b.x); dst[5] = f2bf(b.y); dst[6] = f2bf(b.z); dst[7] = f2bf(b.w);
}
static __device__ __forceinline__ void zero8_store(ushort* dst) {
#pragma unroll
    for (int i = 0; i < 8; i++) dst[i] = 0;
}

// ===========================================================================
// K1: prep_all — e0->bf16, both weight transposes, both rowptrs, self_hr.
// ===========================================================================
__global__ __launch_bounds__(256) void prep_all(
    const float* __restrict__ e0, ushort* __restrict__ e0bf,
    const float* __restrict__ w1e_src, ushort* __restrict__ W1eT,
    const float* __restrict__ w1n_src, ushort* __restrict__ W1nT,
    const int* __restrict__ adj_row, int E, int* __restrict__ rp_adj,
    const int* __restrict__ rw_row, int Erw, int* __restrict__ rp_rw,
    const float* __restrict__ rel_emb, const int* __restrict__ sub,
    const int* __restrict__ rel, ushort* __restrict__ hrbf, int N)
{
    __shared__ float lhs[DIMV];
    int bid = blockIdx.x;
    const int t = threadIdx.x;

    const int NB0 = (N * 28 + 255) >> 8;      // e0bf blocks
    if (bid < NB0) {
        int idx = bid * 256 + t;
        if (idx < N * 28) {
            int n = idx / 28, c = idx % 28;
            ushort* dst = e0bf + (size_t)n * 224 + c * 8;
            if (c < 25) cvt8_store(dst, e0 + (size_t)n * 200 + c * 8);
            else        zero8_store(dst);
        }
        return;
    }
    bid -= NB0;
    if (bid < 364) {                          // W1e transpose (416*224)
        int idx = bid * 256 + t;
        if (idx < 416 * 224) {
            int n = idx / 224, k = idx % 224;
            float v = 0.f;
            if (k < 200) {
                if (n < 200)      v = w1e_src[k * 200 + n];
                else if (n < 400) v = w1e_src[(k + 200) * 200 + (n - 200)];
            }
            W1eT[idx] = f2bf(v);
        }
        return;
    }
    bid -= 364;
    if (bid < 364) {                          // W1n transpose, i = bid/182
        int i = bid / 182;
        int idx = (bid % 182) * 256 + t;
        if (idx < 208 * 224) {
            int n = idx / 224, k = idx % 224;
            float v = (n < 200 && k < 200) ? w1n_src[i * 40000 + k * 200 + n] : 0.f;
            W1nT[(size_t)i * 208 * 224 + idx] = f2bf(v);
        }
        return;
    }
    bid -= 364;
    const int NBr = (N + 256) >> 8;           // rowptr blocks
    if (bid < NBr) {
        int r = bid * 256 + t;
        if (r <= N) rp_adj[r] = lower_bound(adj_row, E, r);
        return;
    }
    bid -= NBr;
    if (bid < NBr) {
        int r = bid * 256 + t;
        if (r <= N) rp_rw[r] = lower_bound(rw_row, Erw, r);
        return;
    }
    bid -= NBr;
    // self_hr: one block per batch element
    {
        const int b = bid;
        if (t < DIMV) lhs[t] = e0[(size_t)sub[b] * DIMV + t];
        __syncthreads();
        if (t >= 224) return;
        if (t < DIMV) {
            const float* R = rel_emb + (size_t)rel[b] * (DIMV * DIMV);
            float acc = 0.f;
            for (int dd = 0; dd < DIMV; dd++)
                acc = fmaf(lhs[dd], R[dd * DIMV + t], acc);
            hrbf[(size_t)b * 224 + t] = f2bf(acc);
        } else {
            hrbf[(size_t)b * 224 + t] = 0;
        }
    }
}

// ===========================================================================
// K2: fused MLP GEMM — edge hidden (y=0,1 -> Pb bf16) and node mask MLP
// (y=2,3).  XCD-swizzled.
// ===========================================================================
__global__ __launch_bounds__(256) void fused_mlp(
    const ushort* __restrict__ e0bf, const ushort* __restrict__ W1eT,
    const ushort* __restrict__ W1nT, ushort* __restrict__ Pb,
    const float* __restrict__ nb1, const float* __restrict__ nW2,
    const float* __restrict__ nb2, const float* __restrict__ neps,
    float* __restrict__ node_mask, int N, int GX)
{
    __shared__ __align__(16) ushort As[2][128 * 40];
    __shared__ __align__(16) ushort Bs[2][208 * 40];
    __shared__ float bsh[208], wsh[208];

    const int r8  = blockIdx.x & 7;
    const int rem = blockIdx.x >> 3;
    const int y   = rem & 3;
    const int q4  = rem >> 2;
    const int x   = r8 + 8 * q4;
    if (x >= GX) return;

    const int t    = threadIdx.x;
    const int lane = t & 63;
    const int w    = t >> 6;
    const int q    = lane >> 4;
    const int ln   = lane & 15;
    const int r0   = x * 128;
    const bool edge = (y < 2);
    const int  i    = y - 2;
    const ushort* Wt = edge ? (W1eT + (size_t)y * 208 * 224)
                            : (W1nT + (size_t)i * 208 * 224);

    if (!edge && t < 208) {
        bsh[t] = (t < 200) ? nb1[i * 200 + t] : 0.f;
        wsh[t] = (t < 200) ? nW2[i * 200 + t] : 0.f;
    }

    f32x4 acc[2][13];
#pragma unroll
    for (int mt = 0; mt < 2; mt++)
#pragma unroll
        for (int nt = 0; nt < 13; nt++) {
            acc[mt][nt][0] = 0.f; acc[mt][nt][1] = 0.f;
            acc[mt][nt][2] = 0.f; acc[mt][nt][3] = 0.f;
        }

    auto stageA = [&](int ks, int buf) {
#pragma unroll
        for (int it = 0; it < 2; it++) {
            int f = t + it * 256;
            int m = f >> 2, c4 = f & 3;
            int g = r0 + m;
            ushort* dst = &As[buf][m * 40 + c4 * 8];
            if (g < N) *(bf16x8*)dst = *(const bf16x8*)&e0bf[(size_t)g * 224 + ks * 32 + c4 * 8];
            else       zero8_store(dst);
        }
    };
    auto stageB = [&](int ks, int buf) {
        for (int f = t; f < 832; f += 256) {
            int n = f >> 2, c4 = f & 3;
            *(bf16x8*)&Bs[buf][n * 40 + c4 * 8] =
                *(const bf16x8*)&Wt[(size_t)n * 224 + ks * 32 + c4 * 8];
        }
    };

    stageA(0, 0); stageB(0, 0);
    __syncthreads();

    for (int ks = 0; ks < 7; ks++) {
        int cur = ks & 1;
        if (ks + 1 < 7) { stageA(ks + 1, cur ^ 1); stageB(ks + 1, cur ^ 1); }
        bf16x8 af0 = *(const bf16x8*)&As[cur][(w * 32 + ln) * 40 + q * 8];
        bf16x8 af1 = *(const bf16x8*)&As[cur][(w * 32 + 16 + ln) * 40 + q * 8];
#pragma unroll
        for (int nt = 0; nt < 13; nt++) {
            bf16x8 bf = *(const bf16x8*)&Bs[cur][(nt * 16 + ln) * 40 + q * 8];
            acc[0][nt] = __builtin_amdgcn_mfma_f32_16x16x32_bf16(af0, bf, acc[0][nt], 0, 0, 0);
            acc[1][nt] = __builtin_amdgcn_mfma_f32_16x16x32_bf16(af1, bf, acc[1][nt], 0, 0, 0);
        }
        __syncthreads();
    }

    if (edge) {
#pragma unroll
        for (int mt = 0; mt < 2; mt++) {
            int gm = r0 + w * 32 + mt * 16 + q * 4;
#pragma unroll
            for (int nt = 0; nt < 13; nt++) {
                int gn = y * 208 + nt * 16 + ln;
                if (gn < 400) {
#pragma unroll
                    for (int r = 0; r < 4; r++)
                        if (gm + r < N) Pb[(size_t)(gm + r) * 400 + gn] = f2bf(acc[mt][nt][r]);
                }
            }
        }
    } else {
        float p[2][4];
#pragma unroll
        for (int mt = 0; mt < 2; mt++)
#pragma unroll
            for (int r = 0; r < 4; r++) {
                float s = 0.f;
#pragma unroll
                for (int nt = 0; nt < 13; nt++) {
                    int n = nt * 16 + ln;
                    float h = fmaxf(acc[mt][nt][r] + bsh[n], 0.f);
                    s = fmaf(h, wsh[n], s);
                }
                p[mt][r] = s;
            }
#pragma unroll
        for (int off = 1; off < 16; off <<= 1)
#pragma unroll
            for (int mt = 0; mt < 2; mt++)
#pragma unroll
                for (int r = 0; r < 4; r++)
                    p[mt][r] += __shfl_xor(p[mt][r], off);

        if (ln == 0) {
            float b2v = nb2[i];
            const float* epsi = neps + (size_t)i * N;
            float* outi = node_mask + (size_t)i * N;
#pragma unroll
            for (int mt = 0; mt < 2; mt++)
#pragma unroll
                for (int r = 0; r < 4; r++) {
                    int g = r0 + w * 32 + mt * 16 + q * 4 + r;
                    if (g < N) outi[g] = gate_fn(epsi[g], p[mt][r] + b2v);
                }
        }
    }
}

// ===========================================================================
// Sparse-chain bodies (packed bf16), 4-edge unrolled for memory-level ||ism.
// 2 rows/vblock, 100 active lanes per 128-thread half.
// ===========================================================================
static __device__ __forceinline__ void spmm_bb_body(
    const uint* __restrict__ x, int xld, const int* __restrict__ rowptr,
    const int* __restrict__ col, const float* __restrict__ val,
    uint* __restrict__ out, int N, int vb, int t)
{
    const int half = t >> 7;
    const int d2   = t & 127;
    const int r    = vb * 2 + half;
    if (d2 >= 100 || r >= N) return;
    const int lo = rowptr[r], hi = rowptr[r + 1];
    float ax0=0.f,ay0=0.f,ax1=0.f,ay1=0.f,ax2=0.f,ay2=0.f,ax3=0.f,ay3=0.f;
    int e = lo;
    for (; e + 3 < hi; e += 4) {
        int c0=col[e], c1=col[e+1], c2=col[e+2], c3=col[e+3];
        float v0=val[e], v1=val[e+1], v2=val[e+2], v3=val[e+3];
        float2 f0=bfp2f(x[(size_t)c0*xld+d2]);
        float2 f1=bfp2f(x[(size_t)c1*xld+d2]);
        float2 f2=bfp2f(x[(size_t)c2*xld+d2]);
        float2 f3=bfp2f(x[(size_t)c3*xld+d2]);
        ax0=fmaf(v0,f0.x,ax0); ay0=fmaf(v0,f0.y,ay0);
        ax1=fmaf(v1,f1.x,ax1); ay1=fmaf(v1,f1.y,ay1);
        ax2=fmaf(v2,f2.x,ax2); ay2=fmaf(v2,f2.y,ay2);
        ax3=fmaf(v3,f3.x,ax3); ay3=fmaf(v3,f3.y,ay3);
    }
    for (; e < hi; e++) {
        float2 f0=bfp2f(x[(size_t)col[e]*xld+d2]);
        ax0=fmaf(val[e],f0.x,ax0); ay0=fmaf(val[e],f0.y,ay0);
    }
    out[(size_t)r*100+d2] = f2bfp((ax0+ax1)+(ax2+ax3), (ay0+ay1)+(ay2+ay3));
}

static __device__ __forceinline__ void dual_body(
    const uint* __restrict__ xA, const uint* __restrict__ xB,
    const int* __restrict__ rowptr, const int* __restrict__ col,
    const float* __restrict__ val, const float* __restrict__ emask,
    float* __restrict__ outA, uint* __restrict__ outB, int N, int vb, int t)
{
    const int half = t >> 7;
    const int d2   = t & 127;
    const int r    = vb * 2 + half;
    if (d2 >= 100 || r >= N) return;
    const int lo = rowptr[r], hi = rowptr[r + 1];
    float ax0=0.f,ay0=0.f,ax1=0.f,ay1=0.f,ax2=0.f,ay2=0.f,ax3=0.f,ay3=0.f;
    float cx0=0.f,cy0=0.f,cx1=0.f,cy1=0.f,cx2=0.f,cy2=0.f,cx3=0.f,cy3=0.f;
    int e = lo;
    for (; e + 3 < hi; e += 4) {
        size_t o0=(size_t)col[e]*100+d2,   o1=(size_t)col[e+1]*100+d2;
        size_t o2=(size_t)col[e+2]*100+d2, o3=(size_t)col[e+3]*100+d2;
        float v0=val[e], v1=val[e+1], v2=val[e+2], v3=val[e+3];
        float m0=v0*emask[e], m1=v1*emask[e+1], m2=v2*emask[e+2], m3=v3*emask[e+3];
        float2 a0=bfp2f(xA[o0]), a1=bfp2f(xA[o1]), a2=bfp2f(xA[o2]), a3=bfp2f(xA[o3]);
        float2 b0=bfp2f(xB[o0]), b1=bfp2f(xB[o1]), b2=bfp2f(xB[o2]), b3=bfp2f(xB[o3]);
        ax0=fmaf(m0,a0.x,ax0); ay0=fmaf(m0,a0.y,ay0);
        ax1=fmaf(m1,a1.x,ax1); ay1=fmaf(m1,a1.y,ay1);
        ax2=fmaf(m2,a2.x,ax2); ay2=fmaf(m2,a2.y,ay2);
        ax3=fmaf(m3,a3.x,ax3); ay3=fmaf(m3,a3.y,ay3);
        cx0=fmaf(v0,b0.x,cx0); cy0=fmaf(v0,b0.y,cy0);
        cx1=fmaf(v1,b1.x,cx1); cy1=fmaf(v1,b1.y,cy1);
        cx2=fmaf(v2,b2.x,cx2); cy2=fmaf(v2,b2.y,cy2);
        cx3=fmaf(v3,b3.x,cx3); cy3=fmaf(v3,b3.y,cy3);
    }
    for (; e < hi; e++) {
        size_t o0=(size_t)col[e]*100+d2;
        float v0=val[e], m0=v0*emask[e];
        float2 a0=bfp2f(xA[o0]); float2 b0=bfp2f(xB[o0]);
        ax0=fmaf(m0,a0.x,ax0); ay0=fmaf(m0,a0.y,ay0);
        cx0=fmaf(v0,b0.x,cx0); cy0=fmaf(v0,b0.y,cy0);
    }
    float2 oA; oA.x=(ax0+ax1)+(ax2+ax3); oA.y=(ay0+ay1)+(ay2+ay3);
    ((float2*)outA)[(size_t)r*100+d2] = oA;
    outB[(size_t)r*100+d2] = f2bfp((cx0+cx1)+(cx2+cx3), (cy0+cy1)+(cy2+cy3));
}

static __device__ __forceinline__ void rwcomb_body(
    const uint* __restrict__ x, const int* __restrict__ rowptr,
    const int* __restrict__ col, const float* __restrict__ val,
    const float* __restrict__ mask, uint* __restrict__ out, int N, int vb, int t)
{
    const int half = t >> 7;
    const int d2   = t & 127;
    const int r    = vb * 2 + half;
    if (d2 >= 100 || r >= N) return;
    const int lo = rowptr[r], hi = rowptr[r + 1];
    float ax0=0.f,ay0=0.f,ax1=0.f,ay1=0.f,ax2=0.f,ay2=0.f,ax3=0.f,ay3=0.f;
    int e = lo;
    for (; e + 3 < hi; e += 4) {
        int c0=col[e], c1=col[e+1], c2=col[e+2], c3=col[e+3];
        float v0=val[e], v1=val[e+1], v2=val[e+2], v3=val[e+3];
        float2 f0=bfp2f(x[(size_t)c0*100+d2]);
        float2 f1=bfp2f(x[(size_t)c1*100+d2]);
        float2 f2=bfp2f(x[(size_t)c2*100+d2]);
        float2 f3=bfp2f(x[(size_t)c3*100+d2]);
        ax0=fmaf(v0,f0.x,ax0); ay0=fmaf(v0,f0.y,ay0);
        ax1=fmaf(v1,f1.x,ax1); ay1=fmaf(v1,f1.y,ay1);
        ax2=fmaf(v2,f2.x,ax2); ay2=fmaf(v2,f2.y,ay2);
        ax3=fmaf(v3,f3.x,ax3); ay3=fmaf(v3,f3.y,ay3);
    }
    for (; e < hi; e++) {
        float2 f0=bfp2f(x[(size_t)col[e]*100+d2]);
        ax0=fmaf(val[e],f0.x,ax0); ay0=fmaf(val[e],f0.y,ay0);
    }
    const float m = mask[r];
    float2 xs = bfp2f(x[(size_t)r*100+d2]);
    float sx=(ax0+ax1)+(ax2+ax3), sy=(ay0+ay1)+(ay2+ay3);
    out[(size_t)r*100+d2] = f2bfp(fmaf(m, xs.x-sx, sx), fmaf(m, xs.y-sy, sy));
}

static __device__ __forceinline__ void bf32_body(
    const uint* __restrict__ x, const int* __restrict__ rowptr,
    const int* __restrict__ col, const float* __restrict__ val,
    float* __restrict__ out, int N, int vb, int t)
{
    const int half = t >> 7;
    const int d2   = t & 127;
    const int r    = vb * 2 + half;
    if (d2 >= 100 || r >= N) return;
    const int lo = rowptr[r], hi = rowptr[r + 1];
    float ax0=0.f,ay0=0.f,ax1=0.f,ay1=0.f,ax2=0.f,ay2=0.f,ax3=0.f,ay3=0.f;
    int e = lo;
    for (; e + 3 < hi; e += 4) {
        int c0=col[e], c1=col[e+1], c2=col[e+2], c3=col[e+3];
        float v0=val[e], v1=val[e+1], v2=val[e+2], v3=val[e+3];
        float2 f0=bfp2f(x[(size_t)c0*100+d2]);
        float2 f1=bfp2f(x[(size_t)c1*100+d2]);
        float2 f2=bfp2f(x[(size_t)c2*100+d2]);
        float2 f3=bfp2f(x[(size_t)c3*100+d2]);
        ax0=fmaf(v0,f0.x,ax0); ay0=fmaf(v0,f0.y,ay0);
        ax1=fmaf(v1,f1.x,ax1); ay1=fmaf(v1,f1.y,ay1);
        ax2=fmaf(v2,f2.x,ax2); ay2=fmaf(v2,f2.y,ay2);
        ax3=fmaf(v3,f3.x,ax3); ay3=fmaf(v3,f3.y,ay3);
    }
    for (; e < hi; e++) {
        float2 f0=bfp2f(x[(size_t)col[e]*100+d2]);
        ax0=fmaf(val[e],f0.x,ax0); ay0=fmaf(val[e],f0.y,ay0);
    }
    float2 o; o.x=(ax0+ax1)+(ax2+ax3); o.y=(ay0+ay1)+(ay2+ay3);
    ((float2*)out)[(size_t)r*100+d2] = o;
}

static __device__ __forceinline__ void egate_body(
    int vb, int t, const uint* __restrict__ P4, const int* __restrict__ rp_adj,
    const int* __restrict__ adj_col, const float* __restrict__ eps,
    float* __restrict__ edge_mask, int N,
    float bb0x, float bb0y, float bb1x, float bb1y,
    float ww0x, float ww0y, float ww1x, float ww1y, float b2v)
{
    const int lane = t & 63;
    const int w    = t >> 6;
    const int gw   = vb * 4 + w;
    const bool act1 = lane < 36;
    const int r_lo = gw * 2;
    const int r_hi = min(r_lo + 2, N);
    for (int r = r_lo; r < r_hi; r++) {
        const uint* Pr = P4 + (size_t)r * 200;
        float2 a0 = bfp2f(Pr[lane]);
        float2 a1; a1.x = 0.f; a1.y = 0.f;
        if (act1) a1 = bfp2f(Pr[64 + lane]);
        a0.x += bb0x; a0.y += bb0y; a1.x += bb1x; a1.y += bb1y;
        const int lo = rp_adj[r], hi = rp_adj[r + 1];
        int e = lo;
        for (; e + 3 < hi; e += 4) {
            const uint* c0 = P4 + (size_t)adj_col[e]     * 200 + 100;
            const uint* c1 = P4 + (size_t)adj_col[e + 1] * 200 + 100;
            const uint* c2 = P4 + (size_t)adj_col[e + 2] * 200 + 100;
            const uint* c3 = P4 + (size_t)adj_col[e + 3] * 200 + 100;
            float2 q0l=bfp2f(c0[lane]), q1l=bfp2f(c1[lane]),
                   q2l=bfp2f(c2[lane]), q3l=bfp2f(c3[lane]);
            float2 q0h,q1h,q2h,q3h;
            q0h.x=q0h.y=q1h.x=q1h.y=q2h.x=q2h.y=q3h.x=q3h.y=0.f;
            if (act1) {
                q0h=bfp2f(c0[64+lane]); q1h=bfp2f(c1[64+lane]);
                q2h=bfp2f(c2[64+lane]); q3h=bfp2f(c3[64+lane]);
            }
            float s0 = fmaxf(a0.x+q0l.x,0.f)*ww0x + fmaxf(a0.y+q0l.y,0.f)*ww0y
                     + fmaxf(a1.x+q0h.x,0.f)*ww1x + fmaxf(a1.y+q0h.y,0.f)*ww1y;
            float s1 = fmaxf(a0.x+q1l.x,0.f)*ww0x + fmaxf(a0.y+q1l.y,0.f)*ww0y
                     + fmaxf(a1.x+q1h.x,0.f)*ww1x + fmaxf(a1.y+q1h.y,0.f)*ww1y;
            float s2 = fmaxf(a0.x+q2l.x,0.f)*ww0x + fmaxf(a0.y+q2l.y,0.f)*ww0y
                     + fmaxf(a1.x+q2h.x,0.f)*ww1x + fmaxf(a1.y+q2h.y,0.f)*ww1y;
            float s3 = fmaxf(a0.x+q3l.x,0.f)*ww0x + fmaxf(a0.y+q3l.y,0.f)*ww0y
                     + fmaxf(a1.x+q3h.x,0.f)*ww1x + fmaxf(a1.y+q3h.y,0.f)*ww1y;
#pragma unroll
            for (int off = 32; off; off >>= 1) {
                s0 += __shfl_xor(s0, off); s1 += __shfl_xor(s1, off);
                s2 += __shfl_xor(s2, off); s3 += __shfl_xor(s3, off);
            }
            if (lane < 4) {
                float sv = (lane == 0) ? s0 : (lane == 1) ? s1 : (lane == 2) ? s2 : s3;
                edge_mask[e + lane] = gate_fn(eps[e + lane], sv + b2v);
            }
        }
        for (; e < hi; e++) {
            const uint* c0 = P4 + (size_t)adj_col[e] * 200 + 100;
            float2 q0l = bfp2f(c0[lane]);
            float2 q0h; q0h.x = q0h.y = 0.f;
            if (act1) q0h = bfp2f(c0[64 + lane]);
            float s0 = fmaxf(a0.x+q0l.x,0.f)*ww0x + fmaxf(a0.y+q0l.y,0.f)*ww0y
                     + fmaxf(a1.x+q0h.x,0.f)*ww1x + fmaxf(a1.y+q0h.y,0.f)*ww1y;
#pragma unroll
            for (int off = 32; off; off >>= 1) s0 += __shfl_xor(s0, off);
            if (lane == 0) edge_mask[e] = gate_fn(eps[e], s0 + b2v);
        }
    }
}

// ===========================================================================
// K3 (cooperative): entire sparse chain, 5 phases with grid-wide syncs.
// ===========================================================================
__global__ __launch_bounds__(256) void sparse_coop(
    const uint* e0u, const int* rp_rw, const int* rw_col, const float* rw_val,
    uint* Tb, const uint* P4, const int* rp_adj, const int* adj_col,
    const float* adj_val, const float* eb1, const float* eW2, const float* eb2,
    const float* eeps, float* edge_mask, const float* e0,
    const float* node_mask, uint* T2b, uint* xndb, uint* Tnb,
    float* x_ed, float* x_nd, int N, int NB_SP, int EGB, int CB)
{
    cg::grid_group grid = cg::this_grid();
    const int t  = threadIdx.x;
    const int nb = gridDim.x;
    const int lane = t & 63;
    const bool act1 = lane < 36;
    const int dA = 2 * lane, dB = 128 + 2 * lane;
    const float bb0x = eb1[dA],  bb0y = eb1[dA + 1];
    const float ww0x = eW2[dA],  ww0y = eW2[dA + 1];
    const float bb1x = act1 ? eb1[dB] : 0.f, bb1y = act1 ? eb1[dB + 1] : 0.f;
    const float ww1x = act1 ? eW2[dB] : 0.f, ww1y = act1 ? eW2[dB + 1] : 0.f;
    const float b2v = eb2[0];

    // Phase A: Tb = rw(e0bf)  ||  edge gate
    for (int vb = blockIdx.x; vb < NB_SP + EGB; vb += nb) {
        if (vb < NB_SP) spmm_bb_body(e0u, 112, rp_rw, rw_col, rw_val, Tb, N, vb, t);
        else egate_body(vb - NB_SP, t, P4, rp_adj, adj_col, eeps, edge_mask, N,
                        bb0x, bb0y, bb1x, bb1y, ww0x, ww0y, ww1x, ww1y, b2v);
    }
    __threadfence(); grid.sync();

    // Phase B: T2b = rw(Tb)  ||  xndb = m0*e0 + (1-m0)*Tb
    for (int vb = blockIdx.x; vb < NB_SP + CB; vb += nb) {
        if (vb < NB_SP) spmm_bb_body(Tb, 100, rp_rw, rw_col, rw_val, T2b, N, vb, t);
        else {
            int idx = (vb - NB_SP) * 256 + t;
            if (idx < N * 100) {
                float m = node_mask[idx / 100];
                float2 a = ((const float2*)e0)[idx];
                float2 b = bfp2f(Tb[idx]);
                xndb[idx] = f2bfp(fmaf(m, a.x - b.x, b.x), fmaf(m, a.y - b.y, b.y));
            }
        }
    }
    __threadfence(); grid.sync();

    // Phase C: x_ed = adj_masked(T2b) [f32 final]; Tnb = adj(xndb)
    for (int vb = blockIdx.x; vb < NB_SP; vb += nb)
        dual_body(T2b, xndb, rp_adj, adj_col, adj_val, edge_mask, x_ed, Tnb, N, vb, t);
    __threadfence(); grid.sync();

    // Phase D: T2b = m1*Tnb + (1-m1)*rw(Tnb)
    for (int vb = blockIdx.x; vb < NB_SP; vb += nb)
        rwcomb_body(Tnb, rp_rw, rw_col, rw_val, node_mask + N, T2b, N, vb, t);
    __threadfence(); grid.sync();

    // Phase E: x_nd = adj(T2b) [f32 final]
    for (int vb = blockIdx.x; vb < NB_SP; vb += nb)
        bf32_body(T2b, rp_adj, adj_col, adj_val, x_nd, N, vb, t);
}

// ===========================================================================
// Fallback path: same bodies as 5 separate kernels (if coop launch fails).
// ===========================================================================
__global__ __launch_bounds__(256) void fb_rw1_egate(
    const uint* __restrict__ e0u, const int* __restrict__ rp_rw,
    const int* __restrict__ rw_col, const float* __restrict__ rw_val,
    uint* __restrict__ Tb, const uint* __restrict__ P4,
    const int* __restrict__ rp_adj, const int* __restrict__ adj_col,
    const float* __restrict__ eb1, const float* __restrict__ eW2,
    const float* __restrict__ eb2, const float* __restrict__ eeps,
    float* __restrict__ edge_mask, int N, int NB_SP)
{
    int bid = blockIdx.x;
    const int t = threadIdx.x;
    if (bid < NB_SP) { spmm_bb_body(e0u, 112, rp_rw, rw_col, rw_val, Tb, N, bid, t); return; }
    const int lane = t & 63;
    const bool act1 = lane < 36;
    const int dA = 2 * lane, dB = 128 + 2 * lane;
    egate_body(bid - NB_SP, t, P4, rp_adj, adj_col, eeps, edge_mask, N,
               eb1[dA], eb1[dA + 1], act1 ? eb1[dB] : 0.f, act1 ? eb1[dB + 1] : 0.f,
               eW2[dA], eW2[dA + 1], act1 ? eW2[dB] : 0.f, act1 ? eW2[dB + 1] : 0.f,
               eb2[0]);
}

__global__ __launch_bounds__(256) void fb_rw2_combine(
    const uint* __restrict__ Tb, const int* __restrict__ rp_rw,
    const int* __restrict__ rw_col, const float* __restrict__ rw_val,
    uint* __restrict__ T2b, const float* __restrict__ e0,
    const float* __restrict__ mask, uint* __restrict__ xndb, int N, int NB_SP)
{
    int bid = blockIdx.x;
    const int t = threadIdx.x;
    if (bid < NB_SP) { spmm_bb_body(Tb, 100, rp_rw, rw_col, rw_val, T2b, N, bid, t); return; }
    int idx = (bid - NB_SP) * 256 + t;
    if (idx >= N * 100) return;
    float m = mask[idx / 100];
    float2 a = ((const float2*)e0)[idx];
    float2 b = bfp2f(Tb[idx]);
    xndb[idx] = f2bfp(fmaf(m, a.x - b.x, b.x), fmaf(m, a.y - b.y, b.y));
}

__global__ __launch_bounds__(256) void fb_dual(
    const uint* __restrict__ xA, const uint* __restrict__ xB,
    const int* __restrict__ rowptr, const int* __restrict__ col,
    const float* __restrict__ val, const float* __restrict__ emask,
    float* __restrict__ outA, uint* __restrict__ outB, int N)
{
    dual_body(xA, xB, rowptr, col, val, emask, outA, outB, N, blockIdx.x, threadIdx.x);
}

__global__ __launch_bounds__(256) void fb_rwcomb(
    const uint* __restrict__ x, const int* __restrict__ rowptr,
    const int* __restrict__ col, const float* __restrict__ val,
    const float* __restrict__ mask, uint* __restrict__ out, int N)
{
    rwcomb_body(x, rowptr, col, val, mask, out, N, blockIdx.x, threadIdx.x);
}

__global__ __launch_bounds__(256) void fb_bf32(
    const uint* __restrict__ x, const int* __restrict__ rowptr,
    const int* __restrict__ col, const float* __restrict__ val,
    float* __restrict__ out, int N)
{
    bf32_body(x, rowptr, col, val, out, N, blockIdx.x, threadIdx.x);
}

// ===========================================================================
// K8: scores = sigmoid(hr @ e0^T).  128 A-rows/block, XCD swizzle.
// ===========================================================================
__global__ __launch_bounds__(256) void scores_mfma(
    const ushort* __restrict__ hrbf, const ushort* __restrict__ e0bf,
    float* __restrict__ scores, int Nent, int GX)
{
    __shared__ __align__(16) ushort Bs[2][192 * 40];

    const int r8  = blockIdx.x & 7;
    const int rem = blockIdx.x >> 3;
    const int y   = rem & 7;
    const int q8  = rem >> 3;
    const int x   = r8 + 8 * q8;
    if (x >= GX) return;

    const int t    = threadIdx.x;
    const int lane = t & 63;
    const int w    = t >> 6;
    const int q    = lane >> 4;
    const int ln   = lane & 15;
    const int n0   = x * 192;
    const int b0   = y * 128;
    const int arow = b0 + w * 32 + ln;

    auto stageB = [&](int ks, int buf) {
        for (int f = t; f < 768; f += 256) {
            int n = f >> 2, c4 = f & 3;
            int gn = n0 + n;
            ushort* dst = &Bs[buf][n * 40 + c4 * 8];
            if (gn < Nent) *(bf16x8*)dst = *(const bf16x8*)&e0bf[(size_t)gn * 224 + ks * 32 + c4 * 8];
            else           zero8_store(dst);
        }
    };
    stageB(0, 0);

    f32x4 acc[2][12];
#pragma unroll
    for (int mt = 0; mt < 2; mt++)
#pragma unroll
        for (int nt = 0; nt < 12; nt++) {
            acc[mt][nt][0] = 0.f; acc[mt][nt][1] = 0.f;
            acc[mt][nt][2] = 0.f; acc[mt][nt][3] = 0.f;
        }

    bf16x8 a0 = *(const bf16x8*)&hrbf[(size_t)arow * 224 + q * 8];
    bf16x8 a1 = *(const bf16x8*)&hrbf[(size_t)(arow + 16) * 224 + q * 8];
    __syncthreads();

    for (int ks = 0; ks < 7; ks++) {
        int cur = ks & 1;
        bf16x8 a0n = a0, a1n = a1;
        if (ks + 1 < 7) {
            stageB(ks + 1, cur ^ 1);
            a0n = *(const bf16x8*)&hrbf[(size_t)arow * 224 + (ks + 1) * 32 + q * 8];
            a1n = *(const bf16x8*)&hrbf[(size_t)(arow + 16) * 224 + (ks + 1) * 32 + q * 8];
        }
#pragma unroll
        for (int nt = 0; nt < 12; nt++) {
            bf16x8 bf = *(const bf16x8*)&Bs[cur][(nt * 16 + ln) * 40 + q * 8];
            acc[0][nt] = __builtin_amdgcn_mfma_f32_16x16x32_bf16(a0, bf, acc[0][nt], 0, 0, 0);
            acc[1][nt] = __builtin_amdgcn_mfma_f32_16x16x32_bf16(a1, bf, acc[1][nt], 0, 0, 0);
        }
        __syncthreads();
        a0 = a0n; a1 = a1n;
    }

#pragma unroll
    for (int mt = 0; mt < 2; mt++) {
        int b = b0 + w * 32 + mt * 16 + q * 4;
#pragma unroll
        for (int nt = 0; nt < 12; nt++) {
            int n = n0 + nt * 16 + ln;
            if (n < Nent) {
#pragma unroll
                for (int r = 0; r < 4; r++)
                    scores[(size_t)(b + r) * Nent + n] = 1.f / (1.f + __expf(-acc[mt][nt][r]));
            }
        }
    }
}

extern "C" void kernel_launch(void* const* d_in, const int* in_sizes, int n_in,
                              void* d_out, int out_size, void* d_ws, size_t ws_size,
                              hipStream_t stream)
{
    const float* e0       = (const float*)d_in[0];
    const float* rel_emb  = (const float*)d_in[1];
    const float* node_W1  = (const float*)d_in[2];
    const float* node_b1  = (const float*)d_in[3];
    const float* node_W2  = (const float*)d_in[4];
    const float* node_b2  = (const float*)d_in[5];
    const float* edge_W1  = (const float*)d_in[6];
    const float* edge_b1  = (const float*)d_in[7];
    const float* edge_W2  = (const float*)d_in[8];
    const float* edge_b2  = (const float*)d_in[9];
    const int*   adj_row  = (const int*)d_in[10];
    const int*   adj_col  = (const int*)d_in[11];
    const float* adj_val  = (const float*)d_in[12];
    const int*   rw_row   = (const int*)d_in[13];
    const int*   rw_col   = (const int*)d_in[14];
    const float* rw_val   = (const float*)d_in[15];
    const float* node_eps = (const float*)d_in[16];
    const float* edge_eps = (const float*)d_in[17];
    const int*   sub      = (const int*)d_in[18];
    const int*   rel      = (const int*)d_in[19];

    const int E   = in_sizes[10];
    const int Erw = in_sizes[13];
    const int N   = in_sizes[0] / DIMV;   // 50000
    const int B   = in_sizes[18];         // 1024

    // workspace layout (~25.6 MB)
    ushort* W1eT = (ushort*)d_ws;                      // 416*224
    ushort* W1nT = W1eT + 416 * 224;                   // 2*208*224
    ushort* e0bf = W1nT + 2 * 208 * 224;               // N*224
    ushort* hrbf = e0bf + (size_t)N * 224;             // B*224
    float*  fb   = (float*)(hrbf + (size_t)B * 224);
    float*  node_mask = fb;                            // 2*N
    float*  edge_mask = node_mask + 2 * (size_t)N;     // E
    int*    rp_adj = (int*)(edge_mask + E);            // N+1
    int*    rp_rw  = rp_adj + (N + 1);                 // N+1

    // output layout: scores (B*N), x_nd (N*200), x_ed (N*200)
    float* out    = (float*)d_out;
    float* scores = out;
    float* x_nd   = out + (size_t)B * N;
    float* x_ed   = x_nd + (size_t)N * DIMV;
    // scores region (204.8 MB) as scratch until the final GEMM:
    uint*   Tb   = (uint*)scores;                      // N*100 uints (20 MB)
    uint*   T2b  = Tb   + (size_t)N * 100;             // N*100
    uint*   xndb = T2b  + (size_t)N * 100;             // N*100
    uint*   Tnb  = xndb + (size_t)N * 100;             // N*100
    uint*   Pb   = Tnb  + (size_t)N * 100;             // N*200 uints = N*400 bf16

    const int NB_SP = (N + 1) / 2;
    const int EGB   = (N + 7) / 8;
    const int CB    = (N * 100 + 255) / 256;
    const int NB0   = (N * 28 + 255) / 256;
    const int NBr   = (N + 256) / 256;
    const int prep_blocks = NB0 + 364 + 364 + NBr + NBr + B;
    const int GXg = (N + 127) / 128;
    const int GXs = (N + 191) / 192;

    // K1: all preps + self_hr
    prep_all<<<prep_blocks, 256, 0, stream>>>(
        e0, e0bf, edge_W1 + 400 * 200, W1eT, node_W1, W1nT,
        adj_row, E, rp_adj, rw_row, Erw, rp_rw,
        rel_emb, sub, rel, hrbf, N);

    // K2: edge hidden GEMM (bf16 Pb) + node mask MLP
    fused_mlp<<<32 * ((GXg + 7) / 8), 256, 0, stream>>>(
        e0bf, W1eT, W1nT, (ushort*)Pb,
        node_b1, node_W2, node_b2, node_eps, node_mask, N, GXg);

    // K3: sparse chain — cooperative if available, else 5 kernels
    static int coop_blocks = -2;
    if (coop_blocks == -2) {
        int nb = 0;
        if (hipOccupancyMaxActiveBlocksPerMultiprocessor(
                &nb, (const void*)sparse_coop, 256, 0) == hipSuccess && nb >= 1)
            coop_blocks = nb * 256;     // 256 CUs on MI355X
        else
            coop_blocks = -1;
    }

    const uint*  e0u_  = (const uint*)e0bf;
    const uint*  P4_   = Pb;
    const float* eb1_  = edge_b1 + 200;
    const float* eW2_  = edge_W2 + 200;
    const float* eb2_  = edge_b2 + 1;
    const float* eeps_ = edge_eps + (size_t)E;
    int N_ = N, NBSP_ = NB_SP, EGB_ = EGB, CB_ = CB;

    bool coop_done = false;
    if (coop_blocks > 0) {
        void* args[] = {
            (void*)&e0u_, (void*)&rp_rw, (void*)&rw_col, (void*)&rw_val,
            (void*)&Tb, (void*)&P4_, (void*)&rp_adj, (void*)&adj_col,
            (void*)&adj_val, (void*)&eb1_, (void*)&eW2_, (void*)&eb2_,
            (void*)&eeps_, (void*)&edge_mask, (void*)&e0,
            (void*)&node_mask, (void*)&T2b, (void*)&xndb, (void*)&Tnb,
            (void*)&x_ed, (void*)&x_nd, (void*)&N_, (void*)&NBSP_,
            (void*)&EGB_, (void*)&CB_ };
        hipError_t le = hipLaunchCooperativeKernel(
            (const void*)sparse_coop, dim3(coop_blocks), dim3(256), args, 0, stream);
        if (le == hipSuccess) coop_done = true;
        else (void)hipGetLastError();
    }
    if (!coop_done) {
        fb_rw1_egate<<<NB_SP + EGB, 256, 0, stream>>>(
            e0u_, rp_rw, rw_col, rw_val, Tb, P4_, rp_adj, adj_col,
            eb1_, eW2_, eb2_, eeps_, edge_mask, N, NB_SP);
        fb_rw2_combine<<<NB_SP + CB, 256, 0, stream>>>(
            Tb, rp_rw, rw_col, rw_val, T2b, e0, node_mask, xndb, N, NB_SP);
        fb_dual<<<NB_SP, 256, 0, stream>>>(
            T2b, xndb, rp_adj, adj_col, adj_val, edge_mask, x_ed, Tnb, N);
        fb_rwcomb<<<NB_SP, 256, 0, stream>>>(
            Tnb, rp_rw, rw_col, rw_val, node_mask + N, T2b, N);
        fb_bf32<<<NB_SP, 256, 0, stream>>>(T2b, rp_adj, adj_col, adj_val, x_nd, N);
    }

    // K8: scores = sigmoid(self_hr @ e0^T)
    scores_mfma<<<64 * ((GXs + 7) / 8), 256, 0, stream>>>(
        hrbf, e0bf, scores, N, GXs);
}

// Round 5
// 862.846 us; speedup vs baseline: 1.9926x; 1.9926x over previous
//
#include <hip/hip_runtime.h>
#include <math.h>

#define DIMV 200
typedef unsigned short ushort;
typedef unsigned int uint;
typedef __attribute__((ext_vector_type(8))) __bf16  bf16x8;
typedef __attribute__((ext_vector_type(4))) float   f32x4;

static __device__ __forceinline__ int lower_bound(const int* __restrict__ a, int n, int key) {
    int lo = 0, hi = n;
    while (lo < hi) {
        int mid = (lo + hi) >> 1;
        if (a[mid] < key) lo = mid + 1; else hi = mid;
    }
    return lo;
}

static __device__ __forceinline__ float gate_fn(float u, float logit) {
    // bias = 1e-4: eps = (2b-1)*u + (1-b); sigmoid((log(eps)-log1p(-eps)+logit)/0.5)
    float ee = fmaf(u, -0.9998f, 0.9999f);
    float g  = (logf(ee) - log1pf(-ee) + logit) * 2.0f;
    return 1.0f / (1.0f + expf(-g));
}

static __device__ __forceinline__ ushort f2bf(float f) {
    unsigned int u = __float_as_uint(f);
    return (ushort)((u + 0x7fffu + ((u >> 16) & 1u)) >> 16);
}
// packed pair: low ushort = dim 2k, high ushort = dim 2k+1
static __device__ __forceinline__ float2 bfp2f(uint u) {
    float2 r;
    r.x = __uint_as_float(u << 16);
    r.y = __uint_as_float(u & 0xffff0000u);
    return r;
}
static __device__ __forceinline__ uint f2bfp(float a, float b) {
    return (uint)f2bf(a) | ((uint)f2bf(b) << 16);
}

static __device__ __forceinline__ void cvt8_store(ushort* dst, const float* src) {
    float4 a = *(const float4*)src;
    float4 b = *(const float4*)(src + 4);
    dst[0] = f2bf(a.x); dst[1] = f2bf(a.y); dst[2] = f2bf(a.z); dst[3] = f2bf(a.w);
    dst[4] = f2bf(b.x); dst[5] = f2bf(b.y); dst[6] = f2bf(b.z); dst[7] = f2bf(b.w);
}
static __device__ __forceinline__ void zero8_store(ushort* dst) {
#pragma unroll
    for (int i = 0; i < 8; i++) dst[i] = 0;
}

// ===========================================================================
// K1: prep_all — e0->bf16, both weight transposes, both rowptrs, self_hr.
// ===========================================================================
__global__ __launch_bounds__(256) void prep_all(
    const float* __restrict__ e0, ushort* __restrict__ e0bf,
    const float* __restrict__ w1e_src, ushort* __restrict__ W1eT,
    const float* __restrict__ w1n_src, ushort* __restrict__ W1nT,
    const int* __restrict__ adj_row, int E, int* __restrict__ rp_adj,
    const int* __restrict__ rw_row, int Erw, int* __restrict__ rp_rw,
    const float* __restrict__ rel_emb, const int* __restrict__ sub,
    const int* __restrict__ rel, ushort* __restrict__ hrbf, int N)
{
    __shared__ float lhs[DIMV];
    int bid = blockIdx.x;
    const int t = threadIdx.x;

    const int NB0 = (N * 28 + 255) >> 8;      // e0bf blocks
    if (bid < NB0) {
        int idx = bid * 256 + t;
        if (idx < N * 28) {
            int n = idx / 28, c = idx % 28;
            ushort* dst = e0bf + (size_t)n * 224 + c * 8;
            if (c < 25) cvt8_store(dst, e0 + (size_t)n * 200 + c * 8);
            else        zero8_store(dst);
        }
        return;
    }
    bid -= NB0;
    if (bid < 364) {                          // W1e transpose (416*224)
        int idx = bid * 256 + t;
        if (idx < 416 * 224) {
            int n = idx / 224, k = idx % 224;
            float v = 0.f;
            if (k < 200) {
                if (n < 200)      v = w1e_src[k * 200 + n];
                else if (n < 400) v = w1e_src[(k + 200) * 200 + (n - 200)];
            }
            W1eT[idx] = f2bf(v);
        }
        return;
    }
    bid -= 364;
    if (bid < 364) {                          // W1n transpose, i = bid/182
        int i = bid / 182;
        int idx = (bid % 182) * 256 + t;
        if (idx < 208 * 224) {
            int n = idx / 224, k = idx % 224;
            float v = (n < 200 && k < 200) ? w1n_src[i * 40000 + k * 200 + n] : 0.f;
            W1nT[(size_t)i * 208 * 224 + idx] = f2bf(v);
        }
        return;
    }
    bid -= 364;
    const int NBr = (N + 256) >> 8;           // rowptr blocks
    if (bid < NBr) {
        int r = bid * 256 + t;
        if (r <= N) rp_adj[r] = lower_bound(adj_row, E, r);
        return;
    }
    bid -= NBr;
    if (bid < NBr) {
        int r = bid * 256 + t;
        if (r <= N) rp_rw[r] = lower_bound(rw_row, Erw, r);
        return;
    }
    bid -= NBr;
    // self_hr: one block per batch element
    {
        const int b = bid;
        if (t < DIMV) lhs[t] = e0[(size_t)sub[b] * DIMV + t];
        __syncthreads();
        if (t >= 224) return;
        if (t < DIMV) {
            const float* R = rel_emb + (size_t)rel[b] * (DIMV * DIMV);
            float acc = 0.f;
            for (int dd = 0; dd < DIMV; dd++)
                acc = fmaf(lhs[dd], R[dd * DIMV + t], acc);
            hrbf[(size_t)b * 224 + t] = f2bf(acc);
        } else {
            hrbf[(size_t)b * 224 + t] = 0;
        }
    }
}

// ===========================================================================
// K2: fused MLP GEMM — edge hidden (y=0,1 -> Pb bf16) and node mask MLP
// (y=2,3).  XCD-swizzled.
// ===========================================================================
__global__ __launch_bounds__(256) void fused_mlp(
    const ushort* __restrict__ e0bf, const ushort* __restrict__ W1eT,
    const ushort* __restrict__ W1nT, ushort* __restrict__ Pb,
    const float* __restrict__ nb1, const float* __restrict__ nW2,
    const float* __restrict__ nb2, const float* __restrict__ neps,
    float* __restrict__ node_mask, int N, int GX)
{
    __shared__ __align__(16) ushort As[2][128 * 40];
    __shared__ __align__(16) ushort Bs[2][208 * 40];
    __shared__ float bsh[208], wsh[208];

    const int r8  = blockIdx.x & 7;
    const int rem = blockIdx.x >> 3;
    const int y   = rem & 3;
    const int q4  = rem >> 2;
    const int x   = r8 + 8 * q4;
    if (x >= GX) return;

    const int t    = threadIdx.x;
    const int lane = t & 63;
    const int w    = t >> 6;
    const int q    = lane >> 4;
    const int ln   = lane & 15;
    const int r0   = x * 128;
    const bool edge = (y < 2);
    const int  i    = y - 2;
    const ushort* Wt = edge ? (W1eT + (size_t)y * 208 * 224)
                            : (W1nT + (size_t)i * 208 * 224);

    if (!edge && t < 208) {
        bsh[t] = (t < 200) ? nb1[i * 200 + t] : 0.f;
        wsh[t] = (t < 200) ? nW2[i * 200 + t] : 0.f;
    }

    f32x4 acc[2][13];
#pragma unroll
    for (int mt = 0; mt < 2; mt++)
#pragma unroll
        for (int nt = 0; nt < 13; nt++) {
            acc[mt][nt][0] = 0.f; acc[mt][nt][1] = 0.f;
            acc[mt][nt][2] = 0.f; acc[mt][nt][3] = 0.f;
        }

    auto stageA = [&](int ks, int buf) {
#pragma unroll
        for (int it = 0; it < 2; it++) {
            int f = t + it * 256;
            int m = f >> 2, c4 = f & 3;
            int g = r0 + m;
            ushort* dst = &As[buf][m * 40 + c4 * 8];
            if (g < N) *(bf16x8*)dst = *(const bf16x8*)&e0bf[(size_t)g * 224 + ks * 32 + c4 * 8];
            else       zero8_store(dst);
        }
    };
    auto stageB = [&](int ks, int buf) {
        for (int f = t; f < 832; f += 256) {
            int n = f >> 2, c4 = f & 3;
            *(bf16x8*)&Bs[buf][n * 40 + c4 * 8] =
                *(const bf16x8*)&Wt[(size_t)n * 224 + ks * 32 + c4 * 8];
        }
    };

    stageA(0, 0); stageB(0, 0);
    __syncthreads();

    for (int ks = 0; ks < 7; ks++) {
        int cur = ks & 1;
        if (ks + 1 < 7) { stageA(ks + 1, cur ^ 1); stageB(ks + 1, cur ^ 1); }
        bf16x8 af0 = *(const bf16x8*)&As[cur][(w * 32 + ln) * 40 + q * 8];
        bf16x8 af1 = *(const bf16x8*)&As[cur][(w * 32 + 16 + ln) * 40 + q * 8];
#pragma unroll
        for (int nt = 0; nt < 13; nt++) {
            bf16x8 bf = *(const bf16x8*)&Bs[cur][(nt * 16 + ln) * 40 + q * 8];
            acc[0][nt] = __builtin_amdgcn_mfma_f32_16x16x32_bf16(af0, bf, acc[0][nt], 0, 0, 0);
            acc[1][nt] = __builtin_amdgcn_mfma_f32_16x16x32_bf16(af1, bf, acc[1][nt], 0, 0, 0);
        }
        __syncthreads();
    }

    if (edge) {
#pragma unroll
        for (int mt = 0; mt < 2; mt++) {
            int gm = r0 + w * 32 + mt * 16 + q * 4;
#pragma unroll
            for (int nt = 0; nt < 13; nt++) {
                int gn = y * 208 + nt * 16 + ln;
                if (gn < 400) {
#pragma unroll
                    for (int r = 0; r < 4; r++)
                        if (gm + r < N) Pb[(size_t)(gm + r) * 400 + gn] = f2bf(acc[mt][nt][r]);
                }
            }
        }
    } else {
        float p[2][4];
#pragma unroll
        for (int mt = 0; mt < 2; mt++)
#pragma unroll
            for (int r = 0; r < 4; r++) {
                float s = 0.f;
#pragma unroll
                for (int nt = 0; nt < 13; nt++) {
                    int n = nt * 16 + ln;
                    float h = fmaxf(acc[mt][nt][r] + bsh[n], 0.f);
                    s = fmaf(h, wsh[n], s);
                }
                p[mt][r] = s;
            }
#pragma unroll
        for (int off = 1; off < 16; off <<= 1)
#pragma unroll
            for (int mt = 0; mt < 2; mt++)
#pragma unroll
                for (int r = 0; r < 4; r++)
                    p[mt][r] += __shfl_xor(p[mt][r], off);

        if (ln == 0) {
            float b2v = nb2[i];
            const float* epsi = neps + (size_t)i * N;
            float* outi = node_mask + (size_t)i * N;
#pragma unroll
            for (int mt = 0; mt < 2; mt++)
#pragma unroll
                for (int r = 0; r < 4; r++) {
                    int g = r0 + w * 32 + mt * 16 + q * 4 + r;
                    if (g < N) outi[g] = gate_fn(epsi[g], p[mt][r] + b2v);
                }
        }
    }
}

// ===========================================================================
// Sparse-chain bodies (packed bf16), 4-edge unrolled for memory-level ||ism.
// 2 rows/vblock, 100 active lanes per 128-thread half.
// ===========================================================================
static __device__ __forceinline__ void spmm_bb_body(
    const uint* __restrict__ x, int xld, const int* __restrict__ rowptr,
    const int* __restrict__ col, const float* __restrict__ val,
    uint* __restrict__ out, int N, int vb, int t)
{
    const int half = t >> 7;
    const int d2   = t & 127;
    const int r    = vb * 2 + half;
    if (d2 >= 100 || r >= N) return;
    const int lo = rowptr[r], hi = rowptr[r + 1];
    float ax0=0.f,ay0=0.f,ax1=0.f,ay1=0.f,ax2=0.f,ay2=0.f,ax3=0.f,ay3=0.f;
    int e = lo;
    for (; e + 3 < hi; e += 4) {
        int c0=col[e], c1=col[e+1], c2=col[e+2], c3=col[e+3];
        float v0=val[e], v1=val[e+1], v2=val[e+2], v3=val[e+3];
        float2 f0=bfp2f(x[(size_t)c0*xld+d2]);
        float2 f1=bfp2f(x[(size_t)c1*xld+d2]);
        float2 f2=bfp2f(x[(size_t)c2*xld+d2]);
        float2 f3=bfp2f(x[(size_t)c3*xld+d2]);
        ax0=fmaf(v0,f0.x,ax0); ay0=fmaf(v0,f0.y,ay0);
        ax1=fmaf(v1,f1.x,ax1); ay1=fmaf(v1,f1.y,ay1);
        ax2=fmaf(v2,f2.x,ax2); ay2=fmaf(v2,f2.y,ay2);
        ax3=fmaf(v3,f3.x,ax3); ay3=fmaf(v3,f3.y,ay3);
    }
    for (; e < hi; e++) {
        float2 f0=bfp2f(x[(size_t)col[e]*xld+d2]);
        ax0=fmaf(val[e],f0.x,ax0); ay0=fmaf(val[e],f0.y,ay0);
    }
    out[(size_t)r*100+d2] = f2bfp((ax0+ax1)+(ax2+ax3), (ay0+ay1)+(ay2+ay3));
}

static __device__ __forceinline__ void dual_body(
    const uint* __restrict__ xA, const uint* __restrict__ xB,
    const int* __restrict__ rowptr, const int* __restrict__ col,
    const float* __restrict__ val, const float* __restrict__ emask,
    float* __restrict__ outA, uint* __restrict__ outB, int N, int vb, int t)
{
    const int half = t >> 7;
    const int d2   = t & 127;
    const int r    = vb * 2 + half;
    if (d2 >= 100 || r >= N) return;
    const int lo = rowptr[r], hi = rowptr[r + 1];
    float ax0=0.f,ay0=0.f,ax1=0.f,ay1=0.f,ax2=0.f,ay2=0.f,ax3=0.f,ay3=0.f;
    float cx0=0.f,cy0=0.f,cx1=0.f,cy1=0.f,cx2=0.f,cy2=0.f,cx3=0.f,cy3=0.f;
    int e = lo;
    for (; e + 3 < hi; e += 4) {
        size_t o0=(size_t)col[e]*100+d2,   o1=(size_t)col[e+1]*100+d2;
        size_t o2=(size_t)col[e+2]*100+d2, o3=(size_t)col[e+3]*100+d2;
        float v0=val[e], v1=val[e+1], v2=val[e+2], v3=val[e+3];
        float m0=v0*emask[e], m1=v1*emask[e+1], m2=v2*emask[e+2], m3=v3*emask[e+3];
        float2 a0=bfp2f(xA[o0]), a1=bfp2f(xA[o1]), a2=bfp2f(xA[o2]), a3=bfp2f(xA[o3]);
        float2 b0=bfp2f(xB[o0]), b1=bfp2f(xB[o1]), b2=bfp2f(xB[o2]), b3=bfp2f(xB[o3]);
        ax0=fmaf(m0,a0.x,ax0); ay0=fmaf(m0,a0.y,ay0);
        ax1=fmaf(m1,a1.x,ax1); ay1=fmaf(m1,a1.y,ay1);
        ax2=fmaf(m2,a2.x,ax2); ay2=fmaf(m2,a2.y,ay2);
        ax3=fmaf(m3,a3.x,ax3); ay3=fmaf(m3,a3.y,ay3);
        cx0=fmaf(v0,b0.x,cx0); cy0=fmaf(v0,b0.y,cy0);
        cx1=fmaf(v1,b1.x,cx1); cy1=fmaf(v1,b1.y,cy1);
        cx2=fmaf(v2,b2.x,cx2); cy2=fmaf(v2,b2.y,cy2);
        cx3=fmaf(v3,b3.x,cx3); cy3=fmaf(v3,b3.y,cy3);
    }
    for (; e < hi; e++) {
        size_t o0=(size_t)col[e]*100+d2;
        float v0=val[e], m0=v0*emask[e];
        float2 a0=bfp2f(xA[o0]); float2 b0=bfp2f(xB[o0]);
        ax0=fmaf(m0,a0.x,ax0); ay0=fmaf(m0,a0.y,ay0);
        cx0=fmaf(v0,b0.x,cx0); cy0=fmaf(v0,b0.y,cy0);
    }
    float2 oA; oA.x=(ax0+ax1)+(ax2+ax3); oA.y=(ay0+ay1)+(ay2+ay3);
    ((float2*)outA)[(size_t)r*100+d2] = oA;
    outB[(size_t)r*100+d2] = f2bfp((cx0+cx1)+(cx2+cx3), (cy0+cy1)+(cy2+cy3));
}

static __device__ __forceinline__ void rwcomb_body(
    const uint* __restrict__ x, const int* __restrict__ rowptr,
    const int* __restrict__ col, const float* __restrict__ val,
    const float* __restrict__ mask, uint* __restrict__ out, int N, int vb, int t)
{
    const int half = t >> 7;
    const int d2   = t & 127;
    const int r    = vb * 2 + half;
    if (d2 >= 100 || r >= N) return;
    const int lo = rowptr[r], hi = rowptr[r + 1];
    float ax0=0.f,ay0=0.f,ax1=0.f,ay1=0.f,ax2=0.f,ay2=0.f,ax3=0.f,ay3=0.f;
    int e = lo;
    for (; e + 3 < hi; e += 4) {
        int c0=col[e], c1=col[e+1], c2=col[e+2], c3=col[e+3];
        float v0=val[e], v1=val[e+1], v2=val[e+2], v3=val[e+3];
        float2 f0=bfp2f(x[(size_t)c0*100+d2]);
        float2 f1=bfp2f(x[(size_t)c1*100+d2]);
        float2 f2=bfp2f(x[(size_t)c2*100+d2]);
        float2 f3=bfp2f(x[(size_t)c3*100+d2]);
        ax0=fmaf(v0,f0.x,ax0); ay0=fmaf(v0,f0.y,ay0);
        ax1=fmaf(v1,f1.x,ax1); ay1=fmaf(v1,f1.y,ay1);
        ax2=fmaf(v2,f2.x,ax2); ay2=fmaf(v2,f2.y,ay2);
        ax3=fmaf(v3,f3.x,ax3); ay3=fmaf(v3,f3.y,ay3);
    }
    for (; e < hi; e++) {
        float2 f0=bfp2f(x[(size_t)col[e]*100+d2]);
        ax0=fmaf(val[e],f0.x,ax0); ay0=fmaf(val[e],f0.y,ay0);
    }
    const float m = mask[r];
    float2 xs = bfp2f(x[(size_t)r*100+d2]);
    float sx=(ax0+ax1)+(ax2+ax3), sy=(ay0+ay1)+(ay2+ay3);
    out[(size_t)r*100+d2] = f2bfp(fmaf(m, xs.x-sx, sx), fmaf(m, xs.y-sy, sy));
}

static __device__ __forceinline__ void bf32_body(
    const uint* __restrict__ x, const int* __restrict__ rowptr,
    const int* __restrict__ col, const float* __restrict__ val,
    float* __restrict__ out, int N, int vb, int t)
{
    const int half = t >> 7;
    const int d2   = t & 127;
    const int r    = vb * 2 + half;
    if (d2 >= 100 || r >= N) return;
    const int lo = rowptr[r], hi = rowptr[r + 1];
    float ax0=0.f,ay0=0.f,ax1=0.f,ay1=0.f,ax2=0.f,ay2=0.f,ax3=0.f,ay3=0.f;
    int e = lo;
    for (; e + 3 < hi; e += 4) {
        int c0=col[e], c1=col[e+1], c2=col[e+2], c3=col[e+3];
        float v0=val[e], v1=val[e+1], v2=val[e+2], v3=val[e+3];
        float2 f0=bfp2f(x[(size_t)c0*100+d2]);
        float2 f1=bfp2f(x[(size_t)c1*100+d2]);
        float2 f2=bfp2f(x[(size_t)c2*100+d2]);
        float2 f3=bfp2f(x[(size_t)c3*100+d2]);
        ax0=fmaf(v0,f0.x,ax0); ay0=fmaf(v0,f0.y,ay0);
        ax1=fmaf(v1,f1.x,ax1); ay1=fmaf(v1,f1.y,ay1);
        ax2=fmaf(v2,f2.x,ax2); ay2=fmaf(v2,f2.y,ay2);
        ax3=fmaf(v3,f3.x,ax3); ay3=fmaf(v3,f3.y,ay3);
    }
    for (; e < hi; e++) {
        float2 f0=bfp2f(x[(size_t)col[e]*100+d2]);
        ax0=fmaf(val[e],f0.x,ax0); ay0=fmaf(val[e],f0.y,ay0);
    }
    float2 o; o.x=(ax0+ax1)+(ax2+ax3); o.y=(ay0+ay1)+(ay2+ay3);
    ((float2*)out)[(size_t)r*100+d2] = o;
}

static __device__ __forceinline__ void egate_body(
    int vb, int t, const uint* __restrict__ P4, const int* __restrict__ rp_adj,
    const int* __restrict__ adj_col, const float* __restrict__ eps,
    float* __restrict__ edge_mask, int N,
    float bb0x, float bb0y, float bb1x, float bb1y,
    float ww0x, float ww0y, float ww1x, float ww1y, float b2v)
{
    const int lane = t & 63;
    const int w    = t >> 6;
    const int gw   = vb * 4 + w;
    const bool act1 = lane < 36;
    const int r_lo = gw * 2;
    const int r_hi = min(r_lo + 2, N);
    for (int r = r_lo; r < r_hi; r++) {
        const uint* Pr = P4 + (size_t)r * 200;
        float2 a0 = bfp2f(Pr[lane]);
        float2 a1; a1.x = 0.f; a1.y = 0.f;
        if (act1) a1 = bfp2f(Pr[64 + lane]);
        a0.x += bb0x; a0.y += bb0y; a1.x += bb1x; a1.y += bb1y;
        const int lo = rp_adj[r], hi = rp_adj[r + 1];
        int e = lo;
        for (; e + 3 < hi; e += 4) {
            const uint* c0 = P4 + (size_t)adj_col[e]     * 200 + 100;
            const uint* c1 = P4 + (size_t)adj_col[e + 1] * 200 + 100;
            const uint* c2 = P4 + (size_t)adj_col[e + 2] * 200 + 100;
            const uint* c3 = P4 + (size_t)adj_col[e + 3] * 200 + 100;
            float2 q0l=bfp2f(c0[lane]), q1l=bfp2f(c1[lane]),
                   q2l=bfp2f(c2[lane]), q3l=bfp2f(c3[lane]);
            float2 q0h,q1h,q2h,q3h;
            q0h.x=q0h.y=q1h.x=q1h.y=q2h.x=q2h.y=q3h.x=q3h.y=0.f;
            if (act1) {
                q0h=bfp2f(c0[64+lane]); q1h=bfp2f(c1[64+lane]);
                q2h=bfp2f(c2[64+lane]); q3h=bfp2f(c3[64+lane]);
            }
            float s0 = fmaxf(a0.x+q0l.x,0.f)*ww0x + fmaxf(a0.y+q0l.y,0.f)*ww0y
                     + fmaxf(a1.x+q0h.x,0.f)*ww1x + fmaxf(a1.y+q0h.y,0.f)*ww1y;
            float s1 = fmaxf(a0.x+q1l.x,0.f)*ww0x + fmaxf(a0.y+q1l.y,0.f)*ww0y
                     + fmaxf(a1.x+q1h.x,0.f)*ww1x + fmaxf(a1.y+q1h.y,0.f)*ww1y;
            float s2 = fmaxf(a0.x+q2l.x,0.f)*ww0x + fmaxf(a0.y+q2l.y,0.f)*ww0y
                     + fmaxf(a1.x+q2h.x,0.f)*ww1x + fmaxf(a1.y+q2h.y,0.f)*ww1y;
            float s3 = fmaxf(a0.x+q3l.x,0.f)*ww0x + fmaxf(a0.y+q3l.y,0.f)*ww0y
                     + fmaxf(a1.x+q3h.x,0.f)*ww1x + fmaxf(a1.y+q3h.y,0.f)*ww1y;
#pragma unroll
            for (int off = 32; off; off >>= 1) {
                s0 += __shfl_xor(s0, off); s1 += __shfl_xor(s1, off);
                s2 += __shfl_xor(s2, off); s3 += __shfl_xor(s3, off);
            }
            if (lane < 4) {
                float sv = (lane == 0) ? s0 : (lane == 1) ? s1 : (lane == 2) ? s2 : s3;
                edge_mask[e + lane] = gate_fn(eps[e + lane], sv + b2v);
            }
        }
        for (; e < hi; e++) {
            const uint* c0 = P4 + (size_t)adj_col[e] * 200 + 100;
            float2 q0l = bfp2f(c0[lane]);
            float2 q0h; q0h.x = q0h.y = 0.f;
            if (act1) q0h = bfp2f(c0[64 + lane]);
            float s0 = fmaxf(a0.x+q0l.x,0.f)*ww0x + fmaxf(a0.y+q0l.y,0.f)*ww0y
                     + fmaxf(a1.x+q0h.x,0.f)*ww1x + fmaxf(a1.y+q0h.y,0.f)*ww1y;
#pragma unroll
            for (int off = 32; off; off >>= 1) s0 += __shfl_xor(s0, off);
            if (lane == 0) edge_mask[e] = gate_fn(eps[e], s0 + b2v);
        }
    }
}

// ===========================================================================
// Sparse chain as 5 separate kernels (R3 structure; coop variant regressed 3x
// — latency-bound chain wants many retiring blocks, not persistent grid).
// ===========================================================================
__global__ __launch_bounds__(256) void k3_rw1_egate(
    const uint* __restrict__ e0u, const int* __restrict__ rp_rw,
    const int* __restrict__ rw_col, const float* __restrict__ rw_val,
    uint* __restrict__ Tb, const uint* __restrict__ P4,
    const int* __restrict__ rp_adj, const int* __restrict__ adj_col,
    const float* __restrict__ eb1, const float* __restrict__ eW2,
    const float* __restrict__ eb2, const float* __restrict__ eeps,
    float* __restrict__ edge_mask, int N, int NB_SP)
{
    int bid = blockIdx.x;
    const int t = threadIdx.x;
    if (bid < NB_SP) { spmm_bb_body(e0u, 112, rp_rw, rw_col, rw_val, Tb, N, bid, t); return; }
    const int lane = t & 63;
    const bool act1 = lane < 36;
    const int dA = 2 * lane, dB = 128 + 2 * lane;
    egate_body(bid - NB_SP, t, P4, rp_adj, adj_col, eeps, edge_mask, N,
               eb1[dA], eb1[dA + 1], act1 ? eb1[dB] : 0.f, act1 ? eb1[dB + 1] : 0.f,
               eW2[dA], eW2[dA + 1], act1 ? eW2[dB] : 0.f, act1 ? eW2[dB + 1] : 0.f,
               eb2[0]);
}

__global__ __launch_bounds__(256) void k4_rw2_combine(
    const uint* __restrict__ Tb, const int* __restrict__ rp_rw,
    const int* __restrict__ rw_col, const float* __restrict__ rw_val,
    uint* __restrict__ T2b, const float* __restrict__ e0,
    const float* __restrict__ mask, uint* __restrict__ xndb, int N, int NB_SP)
{
    int bid = blockIdx.x;
    const int t = threadIdx.x;
    if (bid < NB_SP) { spmm_bb_body(Tb, 100, rp_rw, rw_col, rw_val, T2b, N, bid, t); return; }
    int idx = (bid - NB_SP) * 256 + t;
    if (idx >= N * 100) return;
    float m = mask[idx / 100];
    float2 a = ((const float2*)e0)[idx];
    float2 b = bfp2f(Tb[idx]);
    xndb[idx] = f2bfp(fmaf(m, a.x - b.x, b.x), fmaf(m, a.y - b.y, b.y));
}

__global__ __launch_bounds__(256) void k5_dual(
    const uint* __restrict__ xA, const uint* __restrict__ xB,
    const int* __restrict__ rowptr, const int* __restrict__ col,
    const float* __restrict__ val, const float* __restrict__ emask,
    float* __restrict__ outA, uint* __restrict__ outB, int N)
{
    dual_body(xA, xB, rowptr, col, val, emask, outA, outB, N, blockIdx.x, threadIdx.x);
}

__global__ __launch_bounds__(256) void k6_rwcomb(
    const uint* __restrict__ x, const int* __restrict__ rowptr,
    const int* __restrict__ col, const float* __restrict__ val,
    const float* __restrict__ mask, uint* __restrict__ out, int N)
{
    rwcomb_body(x, rowptr, col, val, mask, out, N, blockIdx.x, threadIdx.x);
}

__global__ __launch_bounds__(256) void k7_bf32(
    const uint* __restrict__ x, const int* __restrict__ rowptr,
    const int* __restrict__ col, const float* __restrict__ val,
    float* __restrict__ out, int N)
{
    bf32_body(x, rowptr, col, val, out, N, blockIdx.x, threadIdx.x);
}

// ===========================================================================
// K8: scores = sigmoid(hr @ e0^T).  128 A-rows/block, XCD swizzle.
// ===========================================================================
__global__ __launch_bounds__(256) void scores_mfma(
    const ushort* __restrict__ hrbf, const ushort* __restrict__ e0bf,
    float* __restrict__ scores, int Nent, int GX)
{
    __shared__ __align__(16) ushort Bs[2][192 * 40];

    const int r8  = blockIdx.x & 7;
    const int rem = blockIdx.x >> 3;
    const int y   = rem & 7;
    const int q8  = rem >> 3;
    const int x   = r8 + 8 * q8;
    if (x >= GX) return;

    const int t    = threadIdx.x;
    const int lane = t & 63;
    const int w    = t >> 6;
    const int q    = lane >> 4;
    const int ln   = lane & 15;
    const int n0   = x * 192;
    const int b0   = y * 128;
    const int arow = b0 + w * 32 + ln;

    auto stageB = [&](int ks, int buf) {
        for (int f = t; f < 768; f += 256) {
            int n = f >> 2, c4 = f & 3;
            int gn = n0 + n;
            ushort* dst = &Bs[buf][n * 40 + c4 * 8];
            if (gn < Nent) *(bf16x8*)dst = *(const bf16x8*)&e0bf[(size_t)gn * 224 + ks * 32 + c4 * 8];
            else           zero8_store(dst);
        }
    };
    stageB(0, 0);

    f32x4 acc[2][12];
#pragma unroll
    for (int mt = 0; mt < 2; mt++)
#pragma unroll
        for (int nt = 0; nt < 12; nt++) {
            acc[mt][nt][0] = 0.f; acc[mt][nt][1] = 0.f;
            acc[mt][nt][2] = 0.f; acc[mt][nt][3] = 0.f;
        }

    bf16x8 a0 = *(const bf16x8*)&hrbf[(size_t)arow * 224 + q * 8];
    bf16x8 a1 = *(const bf16x8*)&hrbf[(size_t)(arow + 16) * 224 + q * 8];
    __syncthreads();

    for (int ks = 0; ks < 7; ks++) {
        int cur = ks & 1;
        bf16x8 a0n = a0, a1n = a1;
        if (ks + 1 < 7) {
            stageB(ks + 1, cur ^ 1);
            a0n = *(const bf16x8*)&hrbf[(size_t)arow * 224 + (ks + 1) * 32 + q * 8];
            a1n = *(const bf16x8*)&hrbf[(size_t)(arow + 16) * 224 + (ks + 1) * 32 + q * 8];
        }
#pragma unroll
        for (int nt = 0; nt < 12; nt++) {
            bf16x8 bf = *(const bf16x8*)&Bs[cur][(nt * 16 + ln) * 40 + q * 8];
            acc[0][nt] = __builtin_amdgcn_mfma_f32_16x16x32_bf16(a0, bf, acc[0][nt], 0, 0, 0);
            acc[1][nt] = __builtin_amdgcn_mfma_f32_16x16x32_bf16(a1, bf, acc[1][nt], 0, 0, 0);
        }
        __syncthreads();
        a0 = a0n; a1 = a1n;
    }

#pragma unroll
    for (int mt = 0; mt < 2; mt++) {
        int b = b0 + w * 32 + mt * 16 + q * 4;
#pragma unroll
        for (int nt = 0; nt < 12; nt++) {
            int n = n0 + nt * 16 + ln;
            if (n < Nent) {
#pragma unroll
                for (int r = 0; r < 4; r++)
                    scores[(size_t)(b + r) * Nent + n] = 1.f / (1.f + __expf(-acc[mt][nt][r]));
            }
        }
    }
}

extern "C" void kernel_launch(void* const* d_in, const int* in_sizes, int n_in,
                              void* d_out, int out_size, void* d_ws, size_t ws_size,
                              hipStream_t stream)
{
    const float* e0       = (const float*)d_in[0];
    const float* rel_emb  = (const float*)d_in[1];
    const float* node_W1  = (const float*)d_in[2];
    const float* node_b1  = (const float*)d_in[3];
    const float* node_W2  = (const float*)d_in[4];
    const float* node_b2  = (const float*)d_in[5];
    const float* edge_W1  = (const float*)d_in[6];
    const float* edge_b1  = (const float*)d_in[7];
    const float* edge_W2  = (const float*)d_in[8];
    const float* edge_b2  = (const float*)d_in[9];
    const int*   adj_row  = (const int*)d_in[10];
    const int*   adj_col  = (const int*)d_in[11];
    const float* adj_val  = (const float*)d_in[12];
    const int*   rw_row   = (const int*)d_in[13];
    const int*   rw_col   = (const int*)d_in[14];
    const float* rw_val   = (const float*)d_in[15];
    const float* node_eps = (const float*)d_in[16];
    const float* edge_eps = (const float*)d_in[17];
    const int*   sub      = (const int*)d_in[18];
    const int*   rel      = (const int*)d_in[19];

    const int E   = in_sizes[10];
    const int Erw = in_sizes[13];
    const int N   = in_sizes[0] / DIMV;   // 50000
    const int B   = in_sizes[18];         // 1024

    // workspace layout (~25.6 MB)
    ushort* W1eT = (ushort*)d_ws;                      // 416*224
    ushort* W1nT = W1eT + 416 * 224;                   // 2*208*224
    ushort* e0bf = W1nT + 2 * 208 * 224;               // N*224
    ushort* hrbf = e0bf + (size_t)N * 224;             // B*224
    float*  fb   = (float*)(hrbf + (size_t)B * 224);
    float*  node_mask = fb;                            // 2*N
    float*  edge_mask = node_mask + 2 * (size_t)N;     // E
    int*    rp_adj = (int*)(edge_mask + E);            // N+1
    int*    rp_rw  = rp_adj + (N + 1);                 // N+1

    // output layout: scores (B*N), x_nd (N*200), x_ed (N*200)
    float* out    = (float*)d_out;
    float* scores = out;
    float* x_nd   = out + (size_t)B * N;
    float* x_ed   = x_nd + (size_t)N * DIMV;
    // scores region (204.8 MB) as scratch until the final GEMM:
    uint*   Tb   = (uint*)scores;                      // N*100 uints (20 MB)
    uint*   T2b  = Tb   + (size_t)N * 100;             // N*100
    uint*   xndb = T2b  + (size_t)N * 100;             // N*100
    uint*   Tnb  = xndb + (size_t)N * 100;             // N*100
    uint*   Pb   = Tnb  + (size_t)N * 100;             // N*200 uints = N*400 bf16

    const int NB_SP = (N + 1) / 2;
    const int EGB   = (N + 7) / 8;
    const int CB    = (N * 100 + 255) / 256;
    const int NB0   = (N * 28 + 255) / 256;
    const int NBr   = (N + 256) / 256;
    const int prep_blocks = NB0 + 364 + 364 + NBr + NBr + B;
    const int GXg = (N + 127) / 128;
    const int GXs = (N + 191) / 192;

    // K1: all preps + self_hr
    prep_all<<<prep_blocks, 256, 0, stream>>>(
        e0, e0bf, edge_W1 + 400 * 200, W1eT, node_W1, W1nT,
        adj_row, E, rp_adj, rw_row, Erw, rp_rw,
        rel_emb, sub, rel, hrbf, N);

    // K2: edge hidden GEMM (bf16 Pb) + node mask MLP
    fused_mlp<<<32 * ((GXg + 7) / 8), 256, 0, stream>>>(
        e0bf, W1eT, W1nT, (ushort*)Pb,
        node_b1, node_W2, node_b2, node_eps, node_mask, N, GXg);

    // K3: Tb = rw(e0bf) + edge gate
    k3_rw1_egate<<<NB_SP + EGB, 256, 0, stream>>>(
        (const uint*)e0bf, rp_rw, rw_col, rw_val, Tb, Pb, rp_adj, adj_col,
        edge_b1 + 200, edge_W2 + 200, edge_b2 + 1, edge_eps + (size_t)E,
        edge_mask, N, NB_SP);

    // K4: T2b = rw(Tb) + xndb = m0*e0 + (1-m0)*Tb
    k4_rw2_combine<<<NB_SP + CB, 256, 0, stream>>>(
        Tb, rp_rw, rw_col, rw_val, T2b, e0, node_mask, xndb, N, NB_SP);

    // K5: x_ed = adj_masked(T2b) [f32 final]; Tnb = adj(xndb)
    k5_dual<<<NB_SP, 256, 0, stream>>>(
        T2b, xndb, rp_adj, adj_col, adj_val, edge_mask, x_ed, Tnb, N);

    // K6: T2b = m1*Tnb + (1-m1)*rw(Tnb)
    k6_rwcomb<<<NB_SP, 256, 0, stream>>>(
        Tnb, rp_rw, rw_col, rw_val, node_mask + N, T2b, N);

    // K7: x_nd = adj(T2b) [f32 final]
    k7_bf32<<<NB_SP, 256, 0, stream>>>(T2b, rp_adj, adj_col, adj_val, x_nd, N);

    // K8: scores = sigmoid(self_hr @ e0^T)
    scores_mfma<<<64 * ((GXs + 7) / 8), 256, 0, stream>>>(
        hrbf, e0bf, scores, N, GXs);
}

// Round 6
// 831.027 us; speedup vs baseline: 2.0689x; 1.0383x over previous
//
#include <hip/hip_runtime.h>
#include <math.h>

#define DIMV 200
typedef unsigned short ushort;
typedef unsigned int uint;
typedef __attribute__((ext_vector_type(8))) __bf16  bf16x8;
typedef __attribute__((ext_vector_type(4))) float   f32x4;

static __device__ __forceinline__ int lower_bound(const int* __restrict__ a, int n, int key) {
    int lo = 0, hi = n;
    while (lo < hi) {
        int mid = (lo + hi) >> 1;
        if (a[mid] < key) lo = mid + 1; else hi = mid;
    }
    return lo;
}

static __device__ __forceinline__ float gate_fn(float u, float logit) {
    // bias = 1e-4: eps = (2b-1)*u + (1-b); sigmoid((log(eps)-log1p(-eps)+logit)/0.5)
    float ee = fmaf(u, -0.9998f, 0.9999f);
    float g  = (logf(ee) - log1pf(-ee) + logit) * 2.0f;
    return 1.0f / (1.0f + expf(-g));
}

static __device__ __forceinline__ ushort f2bf(float f) {
    unsigned int u = __float_as_uint(f);
    return (ushort)((u + 0x7fffu + ((u >> 16) & 1u)) >> 16);
}
// packed pair: low ushort = dim 2k, high ushort = dim 2k+1
static __device__ __forceinline__ float2 bfp2f(uint u) {
    float2 r;
    r.x = __uint_as_float(u << 16);
    r.y = __uint_as_float(u & 0xffff0000u);
    return r;
}
static __device__ __forceinline__ uint f2bfp(float a, float b) {
    return (uint)f2bf(a) | ((uint)f2bf(b) << 16);
}

static __device__ __forceinline__ void cvt8_store(ushort* dst, const float* src) {
    float4 a = *(const float4*)src;
    float4 b = *(const float4*)(src + 4);
    dst[0] = f2bf(a.x); dst[1] = f2bf(a.y); dst[2] = f2bf(a.z); dst[3] = f2bf(a.w);
    dst[4] = f2bf(b.x); dst[5] = f2bf(b.y); dst[6] = f2bf(b.z); dst[7] = f2bf(b.w);
}
static __device__ __forceinline__ void zero8_store(ushort* dst) {
#pragma unroll
    for (int i = 0; i < 8; i++) dst[i] = 0;
}

// ===========================================================================
// K1: prep_all — e0->bf16, both weight transposes, both rowptrs, self_hr.
// ===========================================================================
__global__ __launch_bounds__(256) void prep_all(
    const float* __restrict__ e0, ushort* __restrict__ e0bf,
    const float* __restrict__ w1e_src, ushort* __restrict__ W1eT,
    const float* __restrict__ w1n_src, ushort* __restrict__ W1nT,
    const int* __restrict__ adj_row, int E, int* __restrict__ rp_adj,
    const int* __restrict__ rw_row, int Erw, int* __restrict__ rp_rw,
    const float* __restrict__ rel_emb, const int* __restrict__ sub,
    const int* __restrict__ rel, ushort* __restrict__ hrbf, int N)
{
    __shared__ float lhs[DIMV];
    int bid = blockIdx.x;
    const int t = threadIdx.x;

    const int NB0 = (N * 28 + 255) >> 8;      // e0bf blocks
    if (bid < NB0) {
        int idx = bid * 256 + t;
        if (idx < N * 28) {
            int n = idx / 28, c = idx % 28;
            ushort* dst = e0bf + (size_t)n * 224 + c * 8;
            if (c < 25) cvt8_store(dst, e0 + (size_t)n * 200 + c * 8);
            else        zero8_store(dst);
        }
        return;
    }
    bid -= NB0;
    if (bid < 364) {                          // W1e transpose (416*224)
        int idx = bid * 256 + t;
        if (idx < 416 * 224) {
            int n = idx / 224, k = idx % 224;
            float v = 0.f;
            if (k < 200) {
                if (n < 200)      v = w1e_src[k * 200 + n];
                else if (n < 400) v = w1e_src[(k + 200) * 200 + (n - 200)];
            }
            W1eT[idx] = f2bf(v);
        }
        return;
    }
    bid -= 364;
    if (bid < 364) {                          // W1n transpose, i = bid/182
        int i = bid / 182;
        int idx = (bid % 182) * 256 + t;
        if (idx < 208 * 224) {
            int n = idx / 224, k = idx % 224;
            float v = (n < 200 && k < 200) ? w1n_src[i * 40000 + k * 200 + n] : 0.f;
            W1nT[(size_t)i * 208 * 224 + idx] = f2bf(v);
        }
        return;
    }
    bid -= 364;
    const int NBr = (N + 256) >> 8;           // rowptr blocks
    if (bid < NBr) {
        int r = bid * 256 + t;
        if (r <= N) rp_adj[r] = lower_bound(adj_row, E, r);
        return;
    }
    bid -= NBr;
    if (bid < NBr) {
        int r = bid * 256 + t;
        if (r <= N) rp_rw[r] = lower_bound(rw_row, Erw, r);
        return;
    }
    bid -= NBr;
    // self_hr: one block per batch element
    {
        const int b = bid;
        if (t < DIMV) lhs[t] = e0[(size_t)sub[b] * DIMV + t];
        __syncthreads();
        if (t >= 224) return;
        if (t < DIMV) {
            const float* R = rel_emb + (size_t)rel[b] * (DIMV * DIMV);
            float acc = 0.f;
            for (int dd = 0; dd < DIMV; dd++)
                acc = fmaf(lhs[dd], R[dd * DIMV + t], acc);
            hrbf[(size_t)b * 224 + t] = f2bf(acc);
        } else {
            hrbf[(size_t)b * 224 + t] = 0;
        }
    }
}

// ===========================================================================
// K2: fused MLP GEMM — edge hidden (y=0,1 -> Pb bf16) and node mask MLP
// (y=2,3).  XCD-swizzled.
// ===========================================================================
__global__ __launch_bounds__(256) void fused_mlp(
    const ushort* __restrict__ e0bf, const ushort* __restrict__ W1eT,
    const ushort* __restrict__ W1nT, ushort* __restrict__ Pb,
    const float* __restrict__ nb1, const float* __restrict__ nW2,
    const float* __restrict__ nb2, const float* __restrict__ neps,
    float* __restrict__ node_mask, int N, int GX)
{
    __shared__ __align__(16) ushort As[2][128 * 40];
    __shared__ __align__(16) ushort Bs[2][208 * 40];
    __shared__ float bsh[208], wsh[208];

    const int r8  = blockIdx.x & 7;
    const int rem = blockIdx.x >> 3;
    const int y   = rem & 3;
    const int q4  = rem >> 2;
    const int x   = r8 + 8 * q4;
    if (x >= GX) return;

    const int t    = threadIdx.x;
    const int lane = t & 63;
    const int w    = t >> 6;
    const int q    = lane >> 4;
    const int ln   = lane & 15;
    const int r0   = x * 128;
    const bool edge = (y < 2);
    const int  i    = y - 2;
    const ushort* Wt = edge ? (W1eT + (size_t)y * 208 * 224)
                            : (W1nT + (size_t)i * 208 * 224);

    if (!edge && t < 208) {
        bsh[t] = (t < 200) ? nb1[i * 200 + t] : 0.f;
        wsh[t] = (t < 200) ? nW2[i * 200 + t] : 0.f;
    }

    f32x4 acc[2][13];
#pragma unroll
    for (int mt = 0; mt < 2; mt++)
#pragma unroll
        for (int nt = 0; nt < 13; nt++) {
            acc[mt][nt][0] = 0.f; acc[mt][nt][1] = 0.f;
            acc[mt][nt][2] = 0.f; acc[mt][nt][3] = 0.f;
        }

    auto stageA = [&](int ks, int buf) {
#pragma unroll
        for (int it = 0; it < 2; it++) {
            int f = t + it * 256;
            int m = f >> 2, c4 = f & 3;
            int g = r0 + m;
            ushort* dst = &As[buf][m * 40 + c4 * 8];
            if (g < N) *(bf16x8*)dst = *(const bf16x8*)&e0bf[(size_t)g * 224 + ks * 32 + c4 * 8];
            else       zero8_store(dst);
        }
    };
    auto stageB = [&](int ks, int buf) {
        for (int f = t; f < 832; f += 256) {
            int n = f >> 2, c4 = f & 3;
            *(bf16x8*)&Bs[buf][n * 40 + c4 * 8] =
                *(const bf16x8*)&Wt[(size_t)n * 224 + ks * 32 + c4 * 8];
        }
    };

    stageA(0, 0); stageB(0, 0);
    __syncthreads();

    for (int ks = 0; ks < 7; ks++) {
        int cur = ks & 1;
        if (ks + 1 < 7) { stageA(ks + 1, cur ^ 1); stageB(ks + 1, cur ^ 1); }
        bf16x8 af0 = *(const bf16x8*)&As[cur][(w * 32 + ln) * 40 + q * 8];
        bf16x8 af1 = *(const bf16x8*)&As[cur][(w * 32 + 16 + ln) * 40 + q * 8];
#pragma unroll
        for (int nt = 0; nt < 13; nt++) {
            bf16x8 bf = *(const bf16x8*)&Bs[cur][(nt * 16 + ln) * 40 + q * 8];
            acc[0][nt] = __builtin_amdgcn_mfma_f32_16x16x32_bf16(af0, bf, acc[0][nt], 0, 0, 0);
            acc[1][nt] = __builtin_amdgcn_mfma_f32_16x16x32_bf16(af1, bf, acc[1][nt], 0, 0, 0);
        }
        __syncthreads();
    }

    if (edge) {
#pragma unroll
        for (int mt = 0; mt < 2; mt++) {
            int gm = r0 + w * 32 + mt * 16 + q * 4;
#pragma unroll
            for (int nt = 0; nt < 13; nt++) {
                int gn = y * 208 + nt * 16 + ln;
                if (gn < 400) {
#pragma unroll
                    for (int r = 0; r < 4; r++)
                        if (gm + r < N) Pb[(size_t)(gm + r) * 400 + gn] = f2bf(acc[mt][nt][r]);
                }
            }
        }
    } else {
        float p[2][4];
#pragma unroll
        for (int mt = 0; mt < 2; mt++)
#pragma unroll
            for (int r = 0; r < 4; r++) {
                float s = 0.f;
#pragma unroll
                for (int nt = 0; nt < 13; nt++) {
                    int n = nt * 16 + ln;
                    float h = fmaxf(acc[mt][nt][r] + bsh[n], 0.f);
                    s = fmaf(h, wsh[n], s);
                }
                p[mt][r] = s;
            }
#pragma unroll
        for (int off = 1; off < 16; off <<= 1)
#pragma unroll
            for (int mt = 0; mt < 2; mt++)
#pragma unroll
                for (int r = 0; r < 4; r++)
                    p[mt][r] += __shfl_xor(p[mt][r], off);

        if (ln == 0) {
            float b2v = nb2[i];
            const float* epsi = neps + (size_t)i * N;
            float* outi = node_mask + (size_t)i * N;
#pragma unroll
            for (int mt = 0; mt < 2; mt++)
#pragma unroll
                for (int r = 0; r < 4; r++) {
                    int g = r0 + w * 32 + mt * 16 + q * 4 + r;
                    if (g < N) outi[g] = gate_fn(epsi[g], p[mt][r] + b2v);
                }
        }
    }
}

// ===========================================================================
// Sparse-chain bodies: WAVE-PER-ROW, uint2 (8B) gathers, predicated groups
// (no serial tail).  Lane l<50 handles dims [4l, 4l+3].
// ===========================================================================
static __device__ __forceinline__ void spmm_bb_body(
    const uint* __restrict__ x, int xld, const int* __restrict__ rowptr,
    const int* __restrict__ col, const float* __restrict__ val,
    uint* __restrict__ out, int N, int vb, int t)
{
    const int w = t >> 6, lane = t & 63;
    const int r = vb * 4 + w;
    if (lane >= 50 || r >= N) return;
    const int off = 2 * lane;
    const int lo = rowptr[r], hi = rowptr[r + 1];
    float a0 = 0.f, a1 = 0.f, a2 = 0.f, a3 = 0.f;
    for (int e = lo; e < hi; e += 4) {
        int n = hi - e;
        int c0 = col[e];
        int c1 = n > 1 ? col[e + 1] : c0;
        int c2 = n > 2 ? col[e + 2] : c0;
        int c3 = n > 3 ? col[e + 3] : c0;
        float v0 = val[e];
        float v1 = n > 1 ? val[e + 1] : 0.f;
        float v2 = n > 2 ? val[e + 2] : 0.f;
        float v3 = n > 3 ? val[e + 3] : 0.f;
        uint2 u0 = *(const uint2*)&x[(size_t)c0 * xld + off];
        uint2 u1 = *(const uint2*)&x[(size_t)c1 * xld + off];
        uint2 u2 = *(const uint2*)&x[(size_t)c2 * xld + off];
        uint2 u3 = *(const uint2*)&x[(size_t)c3 * xld + off];
        float2 p;
        p = bfp2f(u0.x); a0 = fmaf(v0, p.x, a0); a1 = fmaf(v0, p.y, a1);
        p = bfp2f(u0.y); a2 = fmaf(v0, p.x, a2); a3 = fmaf(v0, p.y, a3);
        p = bfp2f(u1.x); a0 = fmaf(v1, p.x, a0); a1 = fmaf(v1, p.y, a1);
        p = bfp2f(u1.y); a2 = fmaf(v1, p.x, a2); a3 = fmaf(v1, p.y, a3);
        p = bfp2f(u2.x); a0 = fmaf(v2, p.x, a0); a1 = fmaf(v2, p.y, a1);
        p = bfp2f(u2.y); a2 = fmaf(v2, p.x, a2); a3 = fmaf(v2, p.y, a3);
        p = bfp2f(u3.x); a0 = fmaf(v3, p.x, a0); a1 = fmaf(v3, p.y, a1);
        p = bfp2f(u3.y); a2 = fmaf(v3, p.x, a2); a3 = fmaf(v3, p.y, a3);
    }
    *(uint2*)&out[(size_t)r * 100 + off] = make_uint2(f2bfp(a0, a1), f2bfp(a2, a3));
}

static __device__ __forceinline__ void dual_body(
    const uint* __restrict__ xA, const uint* __restrict__ xB,
    const int* __restrict__ rowptr, const int* __restrict__ col,
    const float* __restrict__ val, const float* __restrict__ emask,
    float* __restrict__ outA, uint* __restrict__ outB, int N, int vb, int t)
{
    const int w = t >> 6, lane = t & 63;
    const int r = vb * 4 + w;
    if (lane >= 50 || r >= N) return;
    const int off = 2 * lane;
    const int lo = rowptr[r], hi = rowptr[r + 1];
    float sA0=0.f,sA1=0.f,sA2=0.f,sA3=0.f;
    float sB0=0.f,sB1=0.f,sB2=0.f,sB3=0.f;
    for (int e = lo; e < hi; e += 4) {
        int n = hi - e;
        int c0 = col[e];
        int c1 = n > 1 ? col[e + 1] : c0;
        int c2 = n > 2 ? col[e + 2] : c0;
        int c3 = n > 3 ? col[e + 3] : c0;
        float v0 = val[e];
        float v1 = n > 1 ? val[e + 1] : 0.f;
        float v2 = n > 2 ? val[e + 2] : 0.f;
        float v3 = n > 3 ? val[e + 3] : 0.f;
        float m0 = v0 * emask[e];
        float m1 = n > 1 ? v1 * emask[e + 1] : 0.f;
        float m2 = n > 2 ? v2 * emask[e + 2] : 0.f;
        float m3 = n > 3 ? v3 * emask[e + 3] : 0.f;
        size_t o0 = (size_t)c0 * 100 + off, o1 = (size_t)c1 * 100 + off;
        size_t o2 = (size_t)c2 * 100 + off, o3 = (size_t)c3 * 100 + off;
        uint2 ua0 = *(const uint2*)&xA[o0], ua1 = *(const uint2*)&xA[o1];
        uint2 ua2 = *(const uint2*)&xA[o2], ua3 = *(const uint2*)&xA[o3];
        uint2 ub0 = *(const uint2*)&xB[o0], ub1 = *(const uint2*)&xB[o1];
        uint2 ub2 = *(const uint2*)&xB[o2], ub3 = *(const uint2*)&xB[o3];
        float2 p;
        p = bfp2f(ua0.x); sA0 = fmaf(m0, p.x, sA0); sA1 = fmaf(m0, p.y, sA1);
        p = bfp2f(ua0.y); sA2 = fmaf(m0, p.x, sA2); sA3 = fmaf(m0, p.y, sA3);
        p = bfp2f(ua1.x); sA0 = fmaf(m1, p.x, sA0); sA1 = fmaf(m1, p.y, sA1);
        p = bfp2f(ua1.y); sA2 = fmaf(m1, p.x, sA2); sA3 = fmaf(m1, p.y, sA3);
        p = bfp2f(ua2.x); sA0 = fmaf(m2, p.x, sA0); sA1 = fmaf(m2, p.y, sA1);
        p = bfp2f(ua2.y); sA2 = fmaf(m2, p.x, sA2); sA3 = fmaf(m2, p.y, sA3);
        p = bfp2f(ua3.x); sA0 = fmaf(m3, p.x, sA0); sA1 = fmaf(m3, p.y, sA1);
        p = bfp2f(ua3.y); sA2 = fmaf(m3, p.x, sA2); sA3 = fmaf(m3, p.y, sA3);
        p = bfp2f(ub0.x); sB0 = fmaf(v0, p.x, sB0); sB1 = fmaf(v0, p.y, sB1);
        p = bfp2f(ub0.y); sB2 = fmaf(v0, p.x, sB2); sB3 = fmaf(v0, p.y, sB3);
        p = bfp2f(ub1.x); sB0 = fmaf(v1, p.x, sB0); sB1 = fmaf(v1, p.y, sB1);
        p = bfp2f(ub1.y); sB2 = fmaf(v1, p.x, sB2); sB3 = fmaf(v1, p.y, sB3);
        p = bfp2f(ub2.x); sB0 = fmaf(v2, p.x, sB0); sB1 = fmaf(v2, p.y, sB1);
        p = bfp2f(ub2.y); sB2 = fmaf(v2, p.x, sB2); sB3 = fmaf(v2, p.y, sB3);
        p = bfp2f(ub3.x); sB0 = fmaf(v3, p.x, sB0); sB1 = fmaf(v3, p.y, sB1);
        p = bfp2f(ub3.y); sB2 = fmaf(v3, p.x, sB2); sB3 = fmaf(v3, p.y, sB3);
    }
    float4 oA; oA.x = sA0; oA.y = sA1; oA.z = sA2; oA.w = sA3;
    *(float4*)&outA[(size_t)r * 200 + 2 * off] = oA;
    *(uint2*)&outB[(size_t)r * 100 + off] = make_uint2(f2bfp(sB0, sB1), f2bfp(sB2, sB3));
}

static __device__ __forceinline__ void rwcomb_body(
    const uint* __restrict__ x, const int* __restrict__ rowptr,
    const int* __restrict__ col, const float* __restrict__ val,
    const float* __restrict__ mask, uint* __restrict__ out, int N, int vb, int t)
{
    const int w = t >> 6, lane = t & 63;
    const int r = vb * 4 + w;
    if (lane >= 50 || r >= N) return;
    const int off = 2 * lane;
    const int lo = rowptr[r], hi = rowptr[r + 1];
    float a0 = 0.f, a1 = 0.f, a2 = 0.f, a3 = 0.f;
    for (int e = lo; e < hi; e += 4) {
        int n = hi - e;
        int c0 = col[e];
        int c1 = n > 1 ? col[e + 1] : c0;
        int c2 = n > 2 ? col[e + 2] : c0;
        int c3 = n > 3 ? col[e + 3] : c0;
        float v0 = val[e];
        float v1 = n > 1 ? val[e + 1] : 0.f;
        float v2 = n > 2 ? val[e + 2] : 0.f;
        float v3 = n > 3 ? val[e + 3] : 0.f;
        uint2 u0 = *(const uint2*)&x[(size_t)c0 * 100 + off];
        uint2 u1 = *(const uint2*)&x[(size_t)c1 * 100 + off];
        uint2 u2 = *(const uint2*)&x[(size_t)c2 * 100 + off];
        uint2 u3 = *(const uint2*)&x[(size_t)c3 * 100 + off];
        float2 p;
        p = bfp2f(u0.x); a0 = fmaf(v0, p.x, a0); a1 = fmaf(v0, p.y, a1);
        p = bfp2f(u0.y); a2 = fmaf(v0, p.x, a2); a3 = fmaf(v0, p.y, a3);
        p = bfp2f(u1.x); a0 = fmaf(v1, p.x, a0); a1 = fmaf(v1, p.y, a1);
        p = bfp2f(u1.y); a2 = fmaf(v1, p.x, a2); a3 = fmaf(v1, p.y, a3);
        p = bfp2f(u2.x); a0 = fmaf(v2, p.x, a0); a1 = fmaf(v2, p.y, a1);
        p = bfp2f(u2.y); a2 = fmaf(v2, p.x, a2); a3 = fmaf(v2, p.y, a3);
        p = bfp2f(u3.x); a0 = fmaf(v3, p.x, a0); a1 = fmaf(v3, p.y, a1);
        p = bfp2f(u3.y); a2 = fmaf(v3, p.x, a2); a3 = fmaf(v3, p.y, a3);
    }
    const float m = mask[r];
    uint2 xs = *(const uint2*)&x[(size_t)r * 100 + off];
    float2 xa = bfp2f(xs.x), xb = bfp2f(xs.y);
    *(uint2*)&out[(size_t)r * 100 + off] = make_uint2(
        f2bfp(fmaf(m, xa.x - a0, a0), fmaf(m, xa.y - a1, a1)),
        f2bfp(fmaf(m, xb.x - a2, a2), fmaf(m, xb.y - a3, a3)));
}

// Final adj pass (deg ~8): 8-wide predicated groups, f32 float4 output.
static __device__ __forceinline__ void bf32_body(
    const uint* __restrict__ x, const int* __restrict__ rowptr,
    const int* __restrict__ col, const float* __restrict__ val,
    float* __restrict__ out, int N, int vb, int t)
{
    const int w = t >> 6, lane = t & 63;
    const int r = vb * 4 + w;
    if (lane >= 50 || r >= N) return;
    const int off = 2 * lane;
    const int lo = rowptr[r], hi = rowptr[r + 1];
    float a0 = 0.f, a1 = 0.f, a2 = 0.f, a3 = 0.f;
    for (int e = lo; e < hi; e += 8) {
        int n = hi - e;
        int c0 = col[e];
        int c1 = n > 1 ? col[e + 1] : c0;
        int c2 = n > 2 ? col[e + 2] : c0;
        int c3 = n > 3 ? col[e + 3] : c0;
        int c4 = n > 4 ? col[e + 4] : c0;
        int c5 = n > 5 ? col[e + 5] : c0;
        int c6 = n > 6 ? col[e + 6] : c0;
        int c7 = n > 7 ? col[e + 7] : c0;
        float v0 = val[e];
        float v1 = n > 1 ? val[e + 1] : 0.f;
        float v2 = n > 2 ? val[e + 2] : 0.f;
        float v3 = n > 3 ? val[e + 3] : 0.f;
        float v4 = n > 4 ? val[e + 4] : 0.f;
        float v5 = n > 5 ? val[e + 5] : 0.f;
        float v6 = n > 6 ? val[e + 6] : 0.f;
        float v7 = n > 7 ? val[e + 7] : 0.f;
        uint2 u0 = *(const uint2*)&x[(size_t)c0 * 100 + off];
        uint2 u1 = *(const uint2*)&x[(size_t)c1 * 100 + off];
        uint2 u2 = *(const uint2*)&x[(size_t)c2 * 100 + off];
        uint2 u3 = *(const uint2*)&x[(size_t)c3 * 100 + off];
        uint2 u4 = *(const uint2*)&x[(size_t)c4 * 100 + off];
        uint2 u5 = *(const uint2*)&x[(size_t)c5 * 100 + off];
        uint2 u6 = *(const uint2*)&x[(size_t)c6 * 100 + off];
        uint2 u7 = *(const uint2*)&x[(size_t)c7 * 100 + off];
        float2 p;
        p = bfp2f(u0.x); a0 = fmaf(v0, p.x, a0); a1 = fmaf(v0, p.y, a1);
        p = bfp2f(u0.y); a2 = fmaf(v0, p.x, a2); a3 = fmaf(v0, p.y, a3);
        p = bfp2f(u1.x); a0 = fmaf(v1, p.x, a0); a1 = fmaf(v1, p.y, a1);
        p = bfp2f(u1.y); a2 = fmaf(v1, p.x, a2); a3 = fmaf(v1, p.y, a3);
        p = bfp2f(u2.x); a0 = fmaf(v2, p.x, a0); a1 = fmaf(v2, p.y, a1);
        p = bfp2f(u2.y); a2 = fmaf(v2, p.x, a2); a3 = fmaf(v2, p.y, a3);
        p = bfp2f(u3.x); a0 = fmaf(v3, p.x, a0); a1 = fmaf(v3, p.y, a1);
        p = bfp2f(u3.y); a2 = fmaf(v3, p.x, a2); a3 = fmaf(v3, p.y, a3);
        p = bfp2f(u4.x); a0 = fmaf(v4, p.x, a0); a1 = fmaf(v4, p.y, a1);
        p = bfp2f(u4.y); a2 = fmaf(v4, p.x, a2); a3 = fmaf(v4, p.y, a3);
        p = bfp2f(u5.x); a0 = fmaf(v5, p.x, a0); a1 = fmaf(v5, p.y, a1);
        p = bfp2f(u5.y); a2 = fmaf(v5, p.x, a2); a3 = fmaf(v5, p.y, a3);
        p = bfp2f(u6.x); a0 = fmaf(v6, p.x, a0); a1 = fmaf(v6, p.y, a1);
        p = bfp2f(u6.y); a2 = fmaf(v6, p.x, a2); a3 = fmaf(v6, p.y, a3);
        p = bfp2f(u7.x); a0 = fmaf(v7, p.x, a0); a1 = fmaf(v7, p.y, a1);
        p = bfp2f(u7.y); a2 = fmaf(v7, p.x, a2); a3 = fmaf(v7, p.y, a3);
    }
    float4 o; o.x = a0; o.y = a1; o.z = a2; o.w = a3;
    *(float4*)&out[(size_t)r * 200 + 2 * off] = o;
}

// Edge gate: wave-per-row, uint2 col-half gathers, predicated 4-groups.
static __device__ __forceinline__ void egate_body(
    int vb, int t, const uint* __restrict__ P4, const int* __restrict__ rp_adj,
    const int* __restrict__ adj_col, const float* __restrict__ eps,
    float* __restrict__ edge_mask, int N,
    const float* __restrict__ eb1, const float* __restrict__ eW2, float b2v)
{
    const int w = t >> 6, lane = t & 63;
    const int r = vb * 4 + w;
    if (r >= N) return;
    const bool act = lane < 50;
    const int off = act ? 2 * lane : 0;
    float4 bb, ww;
    if (act) { bb = *(const float4*)&eb1[4 * lane]; ww = *(const float4*)&eW2[4 * lane]; }
    else     { bb.x = bb.y = bb.z = bb.w = 0.f; ww.x = ww.y = ww.z = ww.w = 0.f; }

    uint2 pr = *(const uint2*)&P4[(size_t)r * 200 + off];
    float2 pA = bfp2f(pr.x), pB = bfp2f(pr.y);
    const float h0 = pA.x + bb.x, h1 = pA.y + bb.y;
    const float h2 = pB.x + bb.z, h3 = pB.y + bb.w;

    const int lo = rp_adj[r], hi = rp_adj[r + 1];
    for (int e = lo; e < hi; e += 4) {
        int n = hi - e;
        int c0 = adj_col[e];
        int c1 = n > 1 ? adj_col[e + 1] : c0;
        int c2 = n > 2 ? adj_col[e + 2] : c0;
        int c3 = n > 3 ? adj_col[e + 3] : c0;
        uint2 q0 = *(const uint2*)&P4[(size_t)c0 * 200 + 100 + off];
        uint2 q1 = *(const uint2*)&P4[(size_t)c1 * 200 + 100 + off];
        uint2 q2 = *(const uint2*)&P4[(size_t)c2 * 200 + 100 + off];
        uint2 q3 = *(const uint2*)&P4[(size_t)c3 * 200 + 100 + off];
        float2 qa, qb;
        qa = bfp2f(q0.x); qb = bfp2f(q0.y);
        float s0 = fmaxf(h0 + qa.x, 0.f) * ww.x + fmaxf(h1 + qa.y, 0.f) * ww.y
                 + fmaxf(h2 + qb.x, 0.f) * ww.z + fmaxf(h3 + qb.y, 0.f) * ww.w;
        qa = bfp2f(q1.x); qb = bfp2f(q1.y);
        float s1 = fmaxf(h0 + qa.x, 0.f) * ww.x + fmaxf(h1 + qa.y, 0.f) * ww.y
                 + fmaxf(h2 + qb.x, 0.f) * ww.z + fmaxf(h3 + qb.y, 0.f) * ww.w;
        qa = bfp2f(q2.x); qb = bfp2f(q2.y);
        float s2 = fmaxf(h0 + qa.x, 0.f) * ww.x + fmaxf(h1 + qa.y, 0.f) * ww.y
                 + fmaxf(h2 + qb.x, 0.f) * ww.z + fmaxf(h3 + qb.y, 0.f) * ww.w;
        qa = bfp2f(q3.x); qb = bfp2f(q3.y);
        float s3 = fmaxf(h0 + qa.x, 0.f) * ww.x + fmaxf(h1 + qa.y, 0.f) * ww.y
                 + fmaxf(h2 + qb.x, 0.f) * ww.z + fmaxf(h3 + qb.y, 0.f) * ww.w;
#pragma unroll
        for (int o = 32; o; o >>= 1) {
            s0 += __shfl_xor(s0, o); s1 += __shfl_xor(s1, o);
            s2 += __shfl_xor(s2, o); s3 += __shfl_xor(s3, o);
        }
        if (lane < 4 && e + lane < hi) {
            float sv = (lane == 0) ? s0 : (lane == 1) ? s1 : (lane == 2) ? s2 : s3;
            edge_mask[e + lane] = gate_fn(eps[e + lane], sv + b2v);
        }
    }
}

// ===========================================================================
// Sparse chain kernels (separate launches; coop variant regressed 3x).
// ===========================================================================
__global__ __launch_bounds__(256) void k3_rw1_egate(
    const uint* __restrict__ e0u, const int* __restrict__ rp_rw,
    const int* __restrict__ rw_col, const float* __restrict__ rw_val,
    uint* __restrict__ Tb, const uint* __restrict__ P4,
    const int* __restrict__ rp_adj, const int* __restrict__ adj_col,
    const float* __restrict__ eb1, const float* __restrict__ eW2,
    const float* __restrict__ eb2, const float* __restrict__ eeps,
    float* __restrict__ edge_mask, int N, int NB_CH)
{
    int bid = blockIdx.x;
    const int t = threadIdx.x;
    if (bid < NB_CH) { spmm_bb_body(e0u, 112, rp_rw, rw_col, rw_val, Tb, N, bid, t); return; }
    egate_body(bid - NB_CH, t, P4, rp_adj, adj_col, eeps, edge_mask, N, eb1, eW2, eb2[0]);
}

__global__ __launch_bounds__(256) void k4_rw2_combine(
    const uint* __restrict__ Tb, const int* __restrict__ rp_rw,
    const int* __restrict__ rw_col, const float* __restrict__ rw_val,
    uint* __restrict__ T2b, const float* __restrict__ e0,
    const float* __restrict__ mask, uint* __restrict__ xndb, int N, int NB_CH)
{
    int bid = blockIdx.x;
    const int t = threadIdx.x;
    if (bid < NB_CH) { spmm_bb_body(Tb, 100, rp_rw, rw_col, rw_val, T2b, N, bid, t); return; }
    int idx = (bid - NB_CH) * 256 + t;
    if (idx >= N * 100) return;
    float m = mask[idx / 100];
    float2 a = ((const float2*)e0)[idx];
    float2 b = bfp2f(Tb[idx]);
    xndb[idx] = f2bfp(fmaf(m, a.x - b.x, b.x), fmaf(m, a.y - b.y, b.y));
}

__global__ __launch_bounds__(256) void k5_dual(
    const uint* __restrict__ xA, const uint* __restrict__ xB,
    const int* __restrict__ rowptr, const int* __restrict__ col,
    const float* __restrict__ val, const float* __restrict__ emask,
    float* __restrict__ outA, uint* __restrict__ outB, int N)
{
    dual_body(xA, xB, rowptr, col, val, emask, outA, outB, N, blockIdx.x, threadIdx.x);
}

__global__ __launch_bounds__(256) void k6_rwcomb(
    const uint* __restrict__ x, const int* __restrict__ rowptr,
    const int* __restrict__ col, const float* __restrict__ val,
    const float* __restrict__ mask, uint* __restrict__ out, int N)
{
    rwcomb_body(x, rowptr, col, val, mask, out, N, blockIdx.x, threadIdx.x);
}

__global__ __launch_bounds__(256) void k7_bf32(
    const uint* __restrict__ x, const int* __restrict__ rowptr,
    const int* __restrict__ col, const float* __restrict__ val,
    float* __restrict__ out, int N)
{
    bf32_body(x, rowptr, col, val, out, N, blockIdx.x, threadIdx.x);
}

// ===========================================================================
// K8: scores = sigmoid(hr @ e0^T).  128 A-rows/block, XCD swizzle.
// ===========================================================================
__global__ __launch_bounds__(256) void scores_mfma(
    const ushort* __restrict__ hrbf, const ushort* __restrict__ e0bf,
    float* __restrict__ scores, int Nent, int GX)
{
    __shared__ __align__(16) ushort Bs[2][192 * 40];

    const int r8  = blockIdx.x & 7;
    const int rem = blockIdx.x >> 3;
    const int y   = rem & 7;
    const int q8  = rem >> 3;
    const int x   = r8 + 8 * q8;
    if (x >= GX) return;

    const int t    = threadIdx.x;
    const int lane = t & 63;
    const int w    = t >> 6;
    const int q    = lane >> 4;
    const int ln   = lane & 15;
    const int n0   = x * 192;
    const int b0   = y * 128;
    const int arow = b0 + w * 32 + ln;

    auto stageB = [&](int ks, int buf) {
        for (int f = t; f < 768; f += 256) {
            int n = f >> 2, c4 = f & 3;
            int gn = n0 + n;
            ushort* dst = &Bs[buf][n * 40 + c4 * 8];
            if (gn < Nent) *(bf16x8*)dst = *(const bf16x8*)&e0bf[(size_t)gn * 224 + ks * 32 + c4 * 8];
            else           zero8_store(dst);
        }
    };
    stageB(0, 0);

    f32x4 acc[2][12];
#pragma unroll
    for (int mt = 0; mt < 2; mt++)
#pragma unroll
        for (int nt = 0; nt < 12; nt++) {
            acc[mt][nt][0] = 0.f; acc[mt][nt][1] = 0.f;
            acc[mt][nt][2] = 0.f; acc[mt][nt][3] = 0.f;
        }

    bf16x8 a0 = *(const bf16x8*)&hrbf[(size_t)arow * 224 + q * 8];
    bf16x8 a1 = *(const bf16x8*)&hrbf[(size_t)(arow + 16) * 224 + q * 8];
    __syncthreads();

    for (int ks = 0; ks < 7; ks++) {
        int cur = ks & 1;
        bf16x8 a0n = a0, a1n = a1;
        if (ks + 1 < 7) {
            stageB(ks + 1, cur ^ 1);
            a0n = *(const bf16x8*)&hrbf[(size_t)arow * 224 + (ks + 1) * 32 + q * 8];
            a1n = *(const bf16x8*)&hrbf[(size_t)(arow + 16) * 224 + (ks + 1) * 32 + q * 8];
        }
#pragma unroll
        for (int nt = 0; nt < 12; nt++) {
            bf16x8 bf = *(const bf16x8*)&Bs[cur][(nt * 16 + ln) * 40 + q * 8];
            acc[0][nt] = __builtin_amdgcn_mfma_f32_16x16x32_bf16(a0, bf, acc[0][nt], 0, 0, 0);
            acc[1][nt] = __builtin_amdgcn_mfma_f32_16x16x32_bf16(a1, bf, acc[1][nt], 0, 0, 0);
        }
        __syncthreads();
        a0 = a0n; a1 = a1n;
    }

#pragma unroll
    for (int mt = 0; mt < 2; mt++) {
        int b = b0 + w * 32 + mt * 16 + q * 4;
#pragma unroll
        for (int nt = 0; nt < 12; nt++) {
            int n = n0 + nt * 16 + ln;
            if (n < Nent) {
#pragma unroll
                for (int r = 0; r < 4; r++)
                    scores[(size_t)(b + r) * Nent + n] = 1.f / (1.f + __expf(-acc[mt][nt][r]));
            }
        }
    }
}

extern "C" void kernel_launch(void* const* d_in, const int* in_sizes, int n_in,
                              void* d_out, int out_size, void* d_ws, size_t ws_size,
                              hipStream_t stream)
{
    const float* e0       = (const float*)d_in[0];
    const float* rel_emb  = (const float*)d_in[1];
    const float* node_W1  = (const float*)d_in[2];
    const float* node_b1  = (const float*)d_in[3];
    const float* node_W2  = (const float*)d_in[4];
    const float* node_b2  = (const float*)d_in[5];
    const float* edge_W1  = (const float*)d_in[6];
    const float* edge_b1  = (const float*)d_in[7];
    const float* edge_W2  = (const float*)d_in[8];
    const float* edge_b2  = (const float*)d_in[9];
    const int*   adj_row  = (const int*)d_in[10];
    const int*   adj_col  = (const int*)d_in[11];
    const float* adj_val  = (const float*)d_in[12];
    const int*   rw_row   = (const int*)d_in[13];
    const int*   rw_col   = (const int*)d_in[14];
    const float* rw_val   = (const float*)d_in[15];
    const float* node_eps = (const float*)d_in[16];
    const float* edge_eps = (const float*)d_in[17];
    const int*   sub      = (const int*)d_in[18];
    const int*   rel      = (const int*)d_in[19];

    const int E   = in_sizes[10];
    const int Erw = in_sizes[13];
    const int N   = in_sizes[0] / DIMV;   // 50000
    const int B   = in_sizes[18];         // 1024

    // workspace layout (~25.6 MB)
    ushort* W1eT = (ushort*)d_ws;                      // 416*224
    ushort* W1nT = W1eT + 416 * 224;                   // 2*208*224
    ushort* e0bf = W1nT + 2 * 208 * 224;               // N*224
    ushort* hrbf = e0bf + (size_t)N * 224;             // B*224
    float*  fb   = (float*)(hrbf + (size_t)B * 224);
    float*  node_mask = fb;                            // 2*N
    float*  edge_mask = node_mask + 2 * (size_t)N;     // E
    int*    rp_adj = (int*)(edge_mask + E);            // N+1
    int*    rp_rw  = rp_adj + (N + 1);                 // N+1

    // output layout: scores (B*N), x_nd (N*200), x_ed (N*200)
    float* out    = (float*)d_out;
    float* scores = out;
    float* x_nd   = out + (size_t)B * N;
    float* x_ed   = x_nd + (size_t)N * DIMV;
    // scores region (204.8 MB) as scratch until the final GEMM:
    uint*   Tb   = (uint*)scores;                      // N*100 uints (20 MB)
    uint*   T2b  = Tb   + (size_t)N * 100;             // N*100
    uint*   xndb = T2b  + (size_t)N * 100;             // N*100
    uint*   Tnb  = xndb + (size_t)N * 100;             // N*100
    uint*   Pb   = Tnb  + (size_t)N * 100;             // N*200 uints = N*400 bf16

    const int NB_CH = (N + 3) / 4;                     // chain blocks (4 rows, wave-per-row)
    const int CB    = (N * 100 + 255) / 256;
    const int NB0   = (N * 28 + 255) / 256;
    const int NBr   = (N + 256) / 256;
    const int prep_blocks = NB0 + 364 + 364 + NBr + NBr + B;
    const int GXg = (N + 127) / 128;
    const int GXs = (N + 191) / 192;

    // K1: all preps + self_hr
    prep_all<<<prep_blocks, 256, 0, stream>>>(
        e0, e0bf, edge_W1 + 400 * 200, W1eT, node_W1, W1nT,
        adj_row, E, rp_adj, rw_row, Erw, rp_rw,
        rel_emb, sub, rel, hrbf, N);

    // K2: edge hidden GEMM (bf16 Pb) + node mask MLP
    fused_mlp<<<32 * ((GXg + 7) / 8), 256, 0, stream>>>(
        e0bf, W1eT, W1nT, (ushort*)Pb,
        node_b1, node_W2, node_b2, node_eps, node_mask, N, GXg);

    // K3: Tb = rw(e0bf) + edge gate
    k3_rw1_egate<<<2 * NB_CH, 256, 0, stream>>>(
        (const uint*)e0bf, rp_rw, rw_col, rw_val, Tb, Pb, rp_adj, adj_col,
        edge_b1 + 200, edge_W2 + 200, edge_b2 + 1, edge_eps + (size_t)E,
        edge_mask, N, NB_CH);

    // K4: T2b = rw(Tb) + xndb = m0*e0 + (1-m0)*Tb
    k4_rw2_combine<<<NB_CH + CB, 256, 0, stream>>>(
        Tb, rp_rw, rw_col, rw_val, T2b, e0, node_mask, xndb, N, NB_CH);

    // K5: x_ed = adj_masked(T2b) [f32 final]; Tnb = adj(xndb)
    k5_dual<<<NB_CH, 256, 0, stream>>>(
        T2b, xndb, rp_adj, adj_col, adj_val, edge_mask, x_ed, Tnb, N);

    // K6: T2b = m1*Tnb + (1-m1)*rw(Tnb)
    k6_rwcomb<<<NB_CH, 256, 0, stream>>>(
        Tnb, rp_rw, rw_col, rw_val, node_mask + N, T2b, N);

    // K7: x_nd = adj(T2b) [f32 final]
    k7_bf32<<<NB_CH, 256, 0, stream>>>(T2b, rp_adj, adj_col, adj_val, x_nd, N);

    // K8: scores = sigmoid(self_hr @ e0^T)
    scores_mfma<<<64 * ((GXs + 7) / 8), 256, 0, stream>>>(
        hrbf, e0bf, scores, N, GXs);
}